// Round 2
// baseline (485.521 us; speedup 1.0000x reference)
//
#include <hip/hip_runtime.h>
#include <hip/hip_bf16.h>

// MHA B=4,S=2048,D=1024,H=16,HD=64 — bf16 MFMA pipeline, fp32 accum/softmax.
// cast x -> bf16 ; transpose+cast W -> [N][K] bf16 ; 3x GEMM (QKV, bf16 out,
// head-permuted, Q pre-scaled) ; MFMA flash attention ; O-proj GEMM -> fp32.

#define B_  4
#define S_  2048
#define D_  1024
#define H_  16
#define HD_ 64
#define M_  (B_*S_)   // 8192

typedef unsigned short u16;
typedef __attribute__((ext_vector_type(8))) short bf16x8;
typedef __attribute__((ext_vector_type(4))) float f32x4;
typedef __attribute__((ext_vector_type(8))) unsigned short ush8;

static __device__ __forceinline__ u16 f2b(float f) {
    unsigned int u = __float_as_uint(f);
    return (u16)((u + 0x7fffu + ((u >> 16) & 1u)) >> 16);
}

#define GLOAD_LDS16(g, l)                                                      \
    __builtin_amdgcn_global_load_lds(                                          \
        (const __attribute__((address_space(1))) void*)(g),                    \
        (__attribute__((address_space(3))) void*)(l), 16, 0, 0)

// ---------------------------------------------------------------------------
// cast fp32 -> bf16, 8 elems/thread
// ---------------------------------------------------------------------------
__global__ __launch_bounds__(256)
void cast_f32_bf16(const float* __restrict__ in, u16* __restrict__ out, int n8)
{
    int i = blockIdx.x * blockDim.x + threadIdx.x;
    const int stride = gridDim.x * blockDim.x;
    for (; i < n8; i += stride) {
        const float4 a = ((const float4*)in)[i*2+0];
        const float4 b = ((const float4*)in)[i*2+1];
        ush8 o;
        o[0]=f2b(a.x); o[1]=f2b(a.y); o[2]=f2b(a.z); o[3]=f2b(a.w);
        o[4]=f2b(b.x); o[5]=f2b(b.y); o[6]=f2b(b.z); o[7]=f2b(b.w);
        ((ush8*)out)[i] = o;
    }
}

// ---------------------------------------------------------------------------
// W [K][N] fp32 -> Wt [N][K] bf16 (64x64 tiles)
// ---------------------------------------------------------------------------
__global__ __launch_bounds__(256)
void transpose_cast(const float* __restrict__ W, u16* __restrict__ Wt)
{
    __shared__ u16 T[64*72];
    const int tid = threadIdx.x;
    const int k0 = blockIdx.x * 64, n0 = blockIdx.y * 64;
    #pragma unroll
    for (int it = 0; it < 4; ++it) {
        const int li = tid + it*256;       // 0..1023
        const int kk = li >> 4;            // 0..63
        const int nc = (li & 15) * 4;
        const float4 w4 = *(const float4*)&W[(size_t)(k0+kk)*D_ + n0 + nc];
        T[(nc+0)*72 + kk] = f2b(w4.x);
        T[(nc+1)*72 + kk] = f2b(w4.y);
        T[(nc+2)*72 + kk] = f2b(w4.z);
        T[(nc+3)*72 + kk] = f2b(w4.w);
    }
    __syncthreads();
    #pragma unroll
    for (int it = 0; it < 2; ++it) {
        const int li = tid + it*256;       // 0..511
        const int nr = li >> 3;            // 0..63
        const int kc = (li & 7) * 8;
        const ush8 v = *(const ush8*)&T[nr*72 + kc];
        *(ush8*)&Wt[(size_t)(n0+nr)*D_ + k0 + kc] = v;
    }
}

// ---------------------------------------------------------------------------
// GEMM: C[M_,D_] = A[M_,D_](bf16) @ Bt[D_,D_]^T(bf16, n-major) + bias (fp32)
// 128x128 tile, BK=32, 256 thr / 4 waves (2x2), acc 4x4 frags of 16x16x32.
// OUT_BF16=1: out bf16 head-permuted [b,h,s,hd], value scaled by oscale.
// OUT_BF16=0: out fp32 row-major [m][n].
// ---------------------------------------------------------------------------
template<int OUT_BF16>
__global__ __launch_bounds__(256)
void gemm_bf16(const u16* __restrict__ A, const u16* __restrict__ Bt,
               const float* __restrict__ bias,
               u16* __restrict__ obf, float* __restrict__ of32, float oscale)
{
    __shared__ u16 As[128*32];   // [m][k]
    __shared__ u16 Bs[128*32];   // [n][k]
    const int tid  = threadIdx.x;
    const int lane = tid & 63;
    const int wave = tid >> 6;
    const int wr = wave >> 1, wc = wave & 1;
    const int bm = blockIdx.x * 128, bn = blockIdx.y * 128;

    // staging: wave stages rows [wave*32, wave*32+32) of both tiles, 2 chunks
    const int srow = wave*32 + (lane >> 2);
    const int sk   = (lane & 3) * 8;
    const u16* gA0 = A  + (size_t)(bm + srow)      * D_ + sk;
    const u16* gA1 = A  + (size_t)(bm + srow + 16) * D_ + sk;
    const u16* gB0 = Bt + (size_t)(bn + srow)      * D_ + sk;
    const u16* gB1 = Bt + (size_t)(bn + srow + 16) * D_ + sk;
    u16* lA0 = &As[(wave*2+0)*512];
    u16* lA1 = &As[(wave*2+1)*512];
    u16* lB0 = &Bs[(wave*2+0)*512];
    u16* lB1 = &Bs[(wave*2+1)*512];

    const f32x4 z4 = {0.f, 0.f, 0.f, 0.f};
    f32x4 acc[4][4];
    #pragma unroll
    for (int i = 0; i < 4; ++i)
        #pragma unroll
        for (int j = 0; j < 4; ++j) acc[i][j] = z4;

    const int cl = lane & 15;
    const int g  = lane >> 4;

    for (int k0 = 0; k0 < D_; k0 += 32) {
        GLOAD_LDS16(gA0 + k0, lA0);
        GLOAD_LDS16(gA1 + k0, lA1);
        GLOAD_LDS16(gB0 + k0, lB0);
        GLOAD_LDS16(gB1 + k0, lB1);
        __syncthreads();

        bf16x8 af[4], bfv[4];
        #pragma unroll
        for (int mf = 0; mf < 4; ++mf)
            af[mf] = *(const bf16x8*)&As[(wr*64 + mf*16 + cl)*32 + g*8];
        #pragma unroll
        for (int nf = 0; nf < 4; ++nf)
            bfv[nf] = *(const bf16x8*)&Bs[(wc*64 + nf*16 + cl)*32 + g*8];
        #pragma unroll
        for (int mf = 0; mf < 4; ++mf)
            #pragma unroll
            for (int nf = 0; nf < 4; ++nf)
                acc[mf][nf] = __builtin_amdgcn_mfma_f32_16x16x32_bf16(
                    af[mf], bfv[nf], acc[mf][nf], 0, 0, 0);
        __syncthreads();
    }

    #pragma unroll
    for (int nf = 0; nf < 4; ++nf) {
        const int col = bn + wc*64 + nf*16 + cl;
        const float bv = bias[col];
        #pragma unroll
        for (int mf = 0; mf < 4; ++mf) {
            #pragma unroll
            for (int r = 0; r < 4; ++r) {
                const int row = bm + wr*64 + mf*16 + g*4 + r;
                const float v = (acc[mf][nf][r] + bv) * oscale;
                if (OUT_BF16) {
                    const int b = row >> 11, s = row & (S_-1);
                    const int h = col >> 6,  d = col & (HD_-1);
                    obf[((size_t)(b*H_ + h)*S_ + s)*HD_ + d] = f2b(v);
                } else {
                    of32[(size_t)row*D_ + col] = v;
                }
            }
        }
    }
}

// ---------------------------------------------------------------------------
// Flash attention (causal), bf16 MFMA, fp32 online softmax.
// Block: 64 q-rows x 1 head. 4 waves x 16 q-rows. KV tiles of 64.
// Qs/Ks/Ps: [64 rows][72 pad] bf16. Vt: V transposed [d][j], j-blocks
// XOR-swizzled by (d>>3) for bank balance.
// ---------------------------------------------------------------------------
__global__ __launch_bounds__(256)
void attn_bf16(const u16* __restrict__ Q, const u16* __restrict__ K,
               const u16* __restrict__ V, u16* __restrict__ out)
{
    __shared__ u16 Qs[64*72];
    __shared__ u16 Ks[64*72];
    __shared__ u16 Vt[64*72];
    __shared__ u16 Ps[64*72];

    const int tid  = threadIdx.x;
    const int lane = tid & 63;
    const int wave = tid >> 6;
    const int cl = lane & 15;
    const int g  = lane >> 4;
    const int qt = blockIdx.x, h = blockIdx.y, b = blockIdx.z;
    const size_t base = ((size_t)(b*H_ + h)) * S_ * HD_;

    // stage Q tile
    #pragma unroll
    for (int p = 0; p < 2; ++p) {
        const int idx = p*256 + tid;
        const int r = idx >> 3, kc = (idx & 7) * 8;
        *(ush8*)&Qs[r*72 + kc] =
            *(const ush8*)&Q[base + (size_t)(qt*64 + r)*HD_ + kc];
    }
    __syncthreads();

    bf16x8 qf[2];
    #pragma unroll
    for (int ks = 0; ks < 2; ++ks)
        qf[ks] = *(const bf16x8*)&Qs[(wave*16 + cl)*72 + ks*32 + g*8];

    const f32x4 z4 = {0.f, 0.f, 0.f, 0.f};
    f32x4 oac[4];
    float m_i[4], l_i[4];
    #pragma unroll
    for (int r = 0; r < 4; ++r) { m_i[r] = -3.0e38f; l_i[r] = 0.f; }
    #pragma unroll
    for (int nf = 0; nf < 4; ++nf) oac[nf] = z4;

    for (int kt = 0; kt <= qt; ++kt) {
        // stage K (row-major) and V (transposed + j-block swizzle)
        #pragma unroll
        for (int p = 0; p < 2; ++p) {
            const int idx = p*256 + tid;
            const int r = idx >> 3, kc = (idx & 7) * 8;
            *(ush8*)&Ks[r*72 + kc] =
                *(const ush8*)&K[base + (size_t)(kt*64 + r)*HD_ + kc];
            const ush8 vv =
                *(const ush8*)&V[base + (size_t)(kt*64 + r)*HD_ + kc];
            const int rb = r >> 3, ro = r & 7;
            #pragma unroll
            for (int e = 0; e < 8; ++e) {
                const int d = kc + e;
                Vt[d*72 + ((rb ^ (d >> 3)) * 8 + ro)] = vv[e];
            }
        }
        __syncthreads();

        // S = Q K^T  (wave's 16 rows x 64 cols)
        f32x4 sac[4];
        #pragma unroll
        for (int nf = 0; nf < 4; ++nf) sac[nf] = z4;
        #pragma unroll
        for (int nf = 0; nf < 4; ++nf)
            #pragma unroll
            for (int ks = 0; ks < 2; ++ks) {
                const bf16x8 kf =
                    *(const bf16x8*)&Ks[(nf*16 + cl)*72 + ks*32 + g*8];
                sac[nf] = __builtin_amdgcn_mfma_f32_16x16x32_bf16(
                    qf[ks], kf, sac[nf], 0, 0, 0);
            }

        // mask + online softmax + P -> LDS
        #pragma unroll
        for (int r = 0; r < 4; ++r) {
            const int iloc = wave*16 + g*4 + r;
            float sv[4];
            #pragma unroll
            for (int nf = 0; nf < 4; ++nf) {
                sv[nf] = sac[nf][r];
                if (kt == qt && (nf*16 + cl) > iloc) sv[nf] = -3.0e38f;
            }
            float mx = fmaxf(fmaxf(sv[0], sv[1]), fmaxf(sv[2], sv[3]));
            #pragma unroll
            for (int msk = 1; msk < 16; msk <<= 1)
                mx = fmaxf(mx, __shfl_xor(mx, msk));
            const float mnew = fmaxf(m_i[r], mx);
            const float es = __expf(m_i[r] - mnew);
            float ls = 0.f;
            float pv[4];
            #pragma unroll
            for (int nf = 0; nf < 4; ++nf) {
                pv[nf] = __expf(sv[nf] - mnew);
                ls += pv[nf];
            }
            #pragma unroll
            for (int msk = 1; msk < 16; msk <<= 1)
                ls += __shfl_xor(ls, msk);
            m_i[r] = mnew;
            l_i[r] = l_i[r] * es + ls;
            #pragma unroll
            for (int nf = 0; nf < 4; ++nf) {
                oac[nf][r] *= es;
                Ps[iloc*72 + nf*16 + cl] = f2b(pv[nf]);
            }
        }

        // O += P V   (within-wave LDS write->read; compiler orders via lgkmcnt)
        bf16x8 pa[2];
        #pragma unroll
        for (int ks = 0; ks < 2; ++ks)
            pa[ks] = *(const bf16x8*)&Ps[(wave*16 + cl)*72 + ks*32 + g*8];
        #pragma unroll
        for (int nf = 0; nf < 4; ++nf) {
            const int d = nf*16 + cl;
            #pragma unroll
            for (int ks = 0; ks < 2; ++ks) {
                const int jb = (ks*4 + g) ^ (d >> 3);
                const bf16x8 vb = *(const bf16x8*)&Vt[d*72 + jb*8];
                oac[nf] = __builtin_amdgcn_mfma_f32_16x16x32_bf16(
                    pa[ks], vb, oac[nf], 0, 0, 0);
            }
        }
        __syncthreads();
    }

    // normalize + write attn buffer [b*S+s][D] bf16, col = h*64 + d
    #pragma unroll
    for (int r = 0; r < 4; ++r) {
        const float inv = 1.f / l_i[r];
        const int srow = qt*64 + wave*16 + g*4 + r;
        #pragma unroll
        for (int nf = 0; nf < 4; ++nf) {
            const int col = h*HD_ + nf*16 + cl;
            out[(size_t)(b*S_ + srow)*D_ + col] = f2b(oac[nf][r] * inv);
        }
    }
}

// ---------------------------------------------------------------------------
extern "C" void kernel_launch(void* const* d_in, const int* in_sizes, int n_in,
                              void* d_out, int out_size, void* d_ws, size_t ws_size,
                              hipStream_t stream)
{
    const float* x    = (const float*)d_in[0];
    const float* Wq_w = (const float*)d_in[1];
    const float* Wq_b = (const float*)d_in[2];
    const float* Wk_w = (const float*)d_in[3];
    const float* Wk_b = (const float*)d_in[4];
    const float* Wv_w = (const float*)d_in[5];
    const float* Wv_b = (const float*)d_in[6];
    const float* Wo_w = (const float*)d_in[7];
    const float* Wo_b = (const float*)d_in[8];
    float* out = (float*)d_out;

    u16* xb    = (u16*)d_ws;                       // [M_][D_] bf16
    u16* wqt   = xb  + (size_t)M_*D_;              // [D_][D_] bf16 (n-major)
    u16* wkt   = wqt + (size_t)D_*D_;
    u16* wvt   = wkt + (size_t)D_*D_;
    u16* wot   = wvt + (size_t)D_*D_;
    u16* q     = wot + (size_t)D_*D_;              // [B,H,S,HD] bf16
    u16* k     = q   + (size_t)M_*D_;
    u16* v     = k   + (size_t)M_*D_;
    u16* attnb = v   + (size_t)M_*D_;              // [M_][D_] bf16

    cast_f32_bf16<<<2048, 256, 0, stream>>>(x, xb, M_*D_/8);
    transpose_cast<<<dim3(16,16), 256, 0, stream>>>(Wq_w, wqt);
    transpose_cast<<<dim3(16,16), 256, 0, stream>>>(Wk_w, wkt);
    transpose_cast<<<dim3(16,16), 256, 0, stream>>>(Wv_w, wvt);
    transpose_cast<<<dim3(16,16), 256, 0, stream>>>(Wo_w, wot);

    const dim3 ggrid(M_/128, D_/128);
    gemm_bf16<1><<<ggrid, 256, 0, stream>>>(xb, wqt, Wq_b, q, nullptr, 0.125f);
    gemm_bf16<1><<<ggrid, 256, 0, stream>>>(xb, wkt, Wk_b, k, nullptr, 1.0f);
    gemm_bf16<1><<<ggrid, 256, 0, stream>>>(xb, wvt, Wv_b, v, nullptr, 1.0f);

    attn_bf16<<<dim3(S_/64, H_, B_), 256, 0, stream>>>(q, k, v, attnb);

    gemm_bf16<0><<<ggrid, 256, 0, stream>>>(attnb, wot, Wo_b, nullptr, out, 1.0f);
}

// Round 3
// 341.036 us; speedup vs baseline: 1.4237x; 1.4237x over previous
//
#include <hip/hip_runtime.h>
#include <hip/hip_bf16.h>

// MHA B=4,S=2048,D=1024,H=16,HD=64 — bf16 MFMA pipeline, fp32 accum/softmax.
// v3: fused QKV GEMM (V written pre-transposed [b,h,d,s]); attn with triangle
// pairing (uniform work), reg-prefetched K/V staging, no in-kernel V transpose.

#define B_  4
#define S_  2048
#define D_  1024
#define H_  16
#define HD_ 64
#define M_  (B_*S_)   // 8192
#define NT_ (S_/64)   // 32 kv/q tiles

typedef unsigned short u16;
typedef __attribute__((ext_vector_type(8))) short bf16x8;
typedef __attribute__((ext_vector_type(4))) float f32x4;
typedef __attribute__((ext_vector_type(8))) unsigned short ush8;

static __device__ __forceinline__ u16 f2b(float f) {
    unsigned int u = __float_as_uint(f);
    return (u16)((u + 0x7fffu + ((u >> 16) & 1u)) >> 16);
}

#define GLOAD_LDS16(g, l)                                                      \
    __builtin_amdgcn_global_load_lds(                                          \
        (const __attribute__((address_space(1))) void*)(g),                    \
        (__attribute__((address_space(3))) void*)(l), 16, 0, 0)

// ---------------------------------------------------------------------------
__global__ __launch_bounds__(256)
void cast_f32_bf16(const float* __restrict__ in, u16* __restrict__ out, int n8)
{
    int i = blockIdx.x * blockDim.x + threadIdx.x;
    const int stride = gridDim.x * blockDim.x;
    for (; i < n8; i += stride) {
        const float4 a = ((const float4*)in)[i*2+0];
        const float4 b = ((const float4*)in)[i*2+1];
        ush8 o;
        o[0]=f2b(a.x); o[1]=f2b(a.y); o[2]=f2b(a.z); o[3]=f2b(a.w);
        o[4]=f2b(b.x); o[5]=f2b(b.y); o[6]=f2b(b.z); o[7]=f2b(b.w);
        ((ush8*)out)[i] = o;
    }
}

// ---------------------------------------------------------------------------
// W [K][N] fp32 -> Wt [N][K] bf16 (64x64 tiles)
// ---------------------------------------------------------------------------
__global__ __launch_bounds__(256)
void transpose_cast(const float* __restrict__ W, u16* __restrict__ Wt)
{
    __shared__ u16 T[64*72];
    const int tid = threadIdx.x;
    const int k0 = blockIdx.x * 64, n0 = blockIdx.y * 64;
    #pragma unroll
    for (int it = 0; it < 4; ++it) {
        const int li = tid + it*256;
        const int kk = li >> 4;
        const int nc = (li & 15) * 4;
        const float4 w4 = *(const float4*)&W[(size_t)(k0+kk)*D_ + n0 + nc];
        T[(nc+0)*72 + kk] = f2b(w4.x);
        T[(nc+1)*72 + kk] = f2b(w4.y);
        T[(nc+2)*72 + kk] = f2b(w4.z);
        T[(nc+3)*72 + kk] = f2b(w4.w);
    }
    __syncthreads();
    #pragma unroll
    for (int it = 0; it < 2; ++it) {
        const int li = tid + it*256;
        const int nr = li >> 3;
        const int kc = (li & 7) * 8;
        const ush8 v = *(const ush8*)&T[nr*72 + kc];
        *(ush8*)&Wt[(size_t)(n0+nr)*D_ + k0 + kc] = v;
    }
}

// ---------------------------------------------------------------------------
// Fused QKV GEMM. sel = blockIdx.y>>3: 0=Q (scaled 1/8, [b,h,s,d]),
// 1=K ([b,h,s,d]), 2=V (transposed out [b,h,d,s]).
// 128x128 tile, BK=32, 4 waves, 16x16x32 bf16 MFMA.
// ---------------------------------------------------------------------------
__global__ __launch_bounds__(256)
void gemm_qkv(const u16* __restrict__ A,
              const u16* __restrict__ wq, const u16* __restrict__ wk,
              const u16* __restrict__ wv,
              const float* __restrict__ bq, const float* __restrict__ bk,
              const float* __restrict__ bv,
              u16* __restrict__ oq, u16* __restrict__ ok, u16* __restrict__ ovt)
{
    __shared__ u16 As[128*32];
    __shared__ u16 Bs[128*32];
    const int tid  = threadIdx.x;
    const int lane = tid & 63;
    const int wave = tid >> 6;
    const int wr = wave >> 1, wc = wave & 1;
    const int bm = blockIdx.x * 128;
    const int sel = blockIdx.y >> 3;
    const int bn = (blockIdx.y & 7) * 128;
    const u16* Bt = sel == 0 ? wq : sel == 1 ? wk : wv;
    const float* bias = sel == 0 ? bq : sel == 1 ? bk : bv;

    const int srow = wave*32 + (lane >> 2);
    const int sk   = (lane & 3) * 8;
    const u16* gA0 = A  + (size_t)(bm + srow)      * D_ + sk;
    const u16* gA1 = A  + (size_t)(bm + srow + 16) * D_ + sk;
    const u16* gB0 = Bt + (size_t)(bn + srow)      * D_ + sk;
    const u16* gB1 = Bt + (size_t)(bn + srow + 16) * D_ + sk;
    u16* lA0 = &As[(wave*2+0)*512];
    u16* lA1 = &As[(wave*2+1)*512];
    u16* lB0 = &Bs[(wave*2+0)*512];
    u16* lB1 = &Bs[(wave*2+1)*512];

    const f32x4 z4 = {0.f, 0.f, 0.f, 0.f};
    f32x4 acc[4][4];
    #pragma unroll
    for (int i = 0; i < 4; ++i)
        #pragma unroll
        for (int j = 0; j < 4; ++j) acc[i][j] = z4;

    const int cl = lane & 15;
    const int g  = lane >> 4;

    for (int k0 = 0; k0 < D_; k0 += 32) {
        GLOAD_LDS16(gA0 + k0, lA0);
        GLOAD_LDS16(gA1 + k0, lA1);
        GLOAD_LDS16(gB0 + k0, lB0);
        GLOAD_LDS16(gB1 + k0, lB1);
        __syncthreads();

        bf16x8 af[4], bfv[4];
        #pragma unroll
        for (int mf = 0; mf < 4; ++mf)
            af[mf] = *(const bf16x8*)&As[(wr*64 + mf*16 + cl)*32 + g*8];
        #pragma unroll
        for (int nf = 0; nf < 4; ++nf)
            bfv[nf] = *(const bf16x8*)&Bs[(wc*64 + nf*16 + cl)*32 + g*8];
        __builtin_amdgcn_s_setprio(1);
        #pragma unroll
        for (int mf = 0; mf < 4; ++mf)
            #pragma unroll
            for (int nf = 0; nf < 4; ++nf)
                acc[mf][nf] = __builtin_amdgcn_mfma_f32_16x16x32_bf16(
                    af[mf], bfv[nf], acc[mf][nf], 0, 0, 0);
        __builtin_amdgcn_s_setprio(0);
        __syncthreads();
    }

    const float oscale = sel == 0 ? 0.125f : 1.0f;
    #pragma unroll
    for (int nf = 0; nf < 4; ++nf) {
        const int col = bn + wc*64 + nf*16 + cl;
        const float bvv = bias[col];
        const int h = col >> 6, d = col & (HD_-1);
        #pragma unroll
        for (int mf = 0; mf < 4; ++mf) {
            #pragma unroll
            for (int r = 0; r < 4; ++r) {
                const int row = bm + wr*64 + mf*16 + g*4 + r;
                const float v = (acc[mf][nf][r] + bvv) * oscale;
                const int b = row >> 11, s = row & (S_-1);
                if (sel == 2) {
                    ovt[((size_t)(b*H_ + h)*HD_ + d)*S_ + s] = f2b(v);
                } else {
                    u16* o = sel == 0 ? oq : ok;
                    o[((size_t)(b*H_ + h)*S_ + s)*HD_ + d] = f2b(v);
                }
            }
        }
    }
}

// ---------------------------------------------------------------------------
// O-proj GEMM: fp32 out, row-major.
// ---------------------------------------------------------------------------
__global__ __launch_bounds__(256)
void gemm_oproj(const u16* __restrict__ A, const u16* __restrict__ Bt,
                const float* __restrict__ bias, float* __restrict__ out)
{
    __shared__ u16 As[128*32];
    __shared__ u16 Bs[128*32];
    const int tid  = threadIdx.x;
    const int lane = tid & 63;
    const int wave = tid >> 6;
    const int wr = wave >> 1, wc = wave & 1;
    const int bm = blockIdx.x * 128, bn = blockIdx.y * 128;

    const int srow = wave*32 + (lane >> 2);
    const int sk   = (lane & 3) * 8;
    const u16* gA0 = A  + (size_t)(bm + srow)      * D_ + sk;
    const u16* gA1 = A  + (size_t)(bm + srow + 16) * D_ + sk;
    const u16* gB0 = Bt + (size_t)(bn + srow)      * D_ + sk;
    const u16* gB1 = Bt + (size_t)(bn + srow + 16) * D_ + sk;
    u16* lA0 = &As[(wave*2+0)*512];
    u16* lA1 = &As[(wave*2+1)*512];
    u16* lB0 = &Bs[(wave*2+0)*512];
    u16* lB1 = &Bs[(wave*2+1)*512];

    const f32x4 z4 = {0.f, 0.f, 0.f, 0.f};
    f32x4 acc[4][4];
    #pragma unroll
    for (int i = 0; i < 4; ++i)
        #pragma unroll
        for (int j = 0; j < 4; ++j) acc[i][j] = z4;

    const int cl = lane & 15;
    const int g  = lane >> 4;

    for (int k0 = 0; k0 < D_; k0 += 32) {
        GLOAD_LDS16(gA0 + k0, lA0);
        GLOAD_LDS16(gA1 + k0, lA1);
        GLOAD_LDS16(gB0 + k0, lB0);
        GLOAD_LDS16(gB1 + k0, lB1);
        __syncthreads();

        bf16x8 af[4], bfv[4];
        #pragma unroll
        for (int mf = 0; mf < 4; ++mf)
            af[mf] = *(const bf16x8*)&As[(wr*64 + mf*16 + cl)*32 + g*8];
        #pragma unroll
        for (int nf = 0; nf < 4; ++nf)
            bfv[nf] = *(const bf16x8*)&Bs[(wc*64 + nf*16 + cl)*32 + g*8];
        __builtin_amdgcn_s_setprio(1);
        #pragma unroll
        for (int mf = 0; mf < 4; ++mf)
            #pragma unroll
            for (int nf = 0; nf < 4; ++nf)
                acc[mf][nf] = __builtin_amdgcn_mfma_f32_16x16x32_bf16(
                    af[mf], bfv[nf], acc[mf][nf], 0, 0, 0);
        __builtin_amdgcn_s_setprio(0);
        __syncthreads();
    }

    #pragma unroll
    for (int nf = 0; nf < 4; ++nf) {
        const int col = bn + wc*64 + nf*16 + cl;
        const float bvv = bias[col];
        #pragma unroll
        for (int mf = 0; mf < 4; ++mf) {
            #pragma unroll
            for (int r = 0; r < 4; ++r) {
                const int row = bm + wr*64 + mf*16 + g*4 + r;
                out[(size_t)row*D_ + col] = acc[mf][nf][r] + bvv;
            }
        }
    }
}

// ---------------------------------------------------------------------------
// Flash attention (causal). Triangle pairing: block handles q-tiles `pair`
// and `31-pair` (uniform 33 kv-tile-units). 4 waves x 16 q-rows. KV tiles 64.
// K from [b,h,s,d]; V pre-transposed [b,h,d,s]. K/V reg-prefetched (T14).
// Q frags straight from global. fp32 online softmax, 16-lane shfl reduce.
// ---------------------------------------------------------------------------
__global__ __launch_bounds__(256, 4)
void attn_bf16(const u16* __restrict__ Q, const u16* __restrict__ K,
               const u16* __restrict__ Vt, u16* __restrict__ out)
{
    __shared__ u16 Ks[64*72];
    __shared__ u16 Vs[64*72];   // [d][j] tile of V^T
    __shared__ u16 Ps[64*72];

    const int tid  = threadIdx.x;
    const int lane = tid & 63;
    const int wave = tid >> 6;
    const int cl = lane & 15;
    const int g  = lane >> 4;
    const int pair = blockIdx.x, h = blockIdx.y, b = blockIdx.z;
    const size_t base  = ((size_t)(b*H_ + h)) * S_ * HD_;   // Q,K: [s][d]
    const size_t vbase = ((size_t)(b*H_ + h)) * HD_ * S_;   // Vt: [d][s]

    int qt = pair;
    const int n0 = pair + 1;          // tiles in part 0; total = NT_+1 = 33

    // staging chunk coords: thread stages chunks {tid, tid+256} of 512
    const int r0  = tid >> 3;          // 0..31 (+32 for p=1)
    const int kc0 = (tid & 7) * 8;

    // Q frags (part 0)
    bf16x8 qf[2];
    #pragma unroll
    for (int ks = 0; ks < 2; ++ks)
        qf[ks] = *(const bf16x8*)&Q[base +
            (size_t)(qt*64 + wave*16 + cl)*HD_ + ks*32 + g*8];

    // prefetch tile 0
    ush8 kreg[2], vreg[2];
    #pragma unroll
    for (int p = 0; p < 2; ++p) {
        kreg[p] = *(const ush8*)&K [base  + (size_t)(r0 + p*32)*HD_ + kc0];
        vreg[p] = *(const ush8*)&Vt[vbase + (size_t)(r0 + p*32)*S_  + kc0];
    }

    const f32x4 z4 = {0.f, 0.f, 0.f, 0.f};
    f32x4 oac[4];
    float m_i[4], l_i[4];
    #pragma unroll
    for (int r = 0; r < 4; ++r) { m_i[r] = -3.0e38f; l_i[r] = 0.f; }
    #pragma unroll
    for (int nf = 0; nf < 4; ++nf) oac[nf] = z4;

    for (int t = 0; t < NT_ + 1; ++t) {
        const bool second = (t >= n0);
        const int kt = second ? t - n0 : t;

        if (t == n0) {
            // part-0 epilogue + reinit for part 1 (qt = 31-pair)
            #pragma unroll
            for (int r = 0; r < 4; ++r) {
                const float inv = 1.f / l_i[r];
                const int srow = qt*64 + wave*16 + g*4 + r;
                #pragma unroll
                for (int nf = 0; nf < 4; ++nf)
                    out[(size_t)(b*S_ + srow)*D_ + h*HD_ + nf*16 + cl] =
                        f2b(oac[nf][r] * inv);
            }
            qt = NT_ - 1 - pair;
            #pragma unroll
            for (int ks = 0; ks < 2; ++ks)
                qf[ks] = *(const bf16x8*)&Q[base +
                    (size_t)(qt*64 + wave*16 + cl)*HD_ + ks*32 + g*8];
            #pragma unroll
            for (int r = 0; r < 4; ++r) { m_i[r] = -3.0e38f; l_i[r] = 0.f; }
            #pragma unroll
            for (int nf = 0; nf < 4; ++nf) oac[nf] = z4;
        }

        // commit prefetched tile to LDS
        #pragma unroll
        for (int p = 0; p < 2; ++p) {
            *(ush8*)&Ks[(r0 + p*32)*72 + kc0] = kreg[p];
            *(ush8*)&Vs[(r0 + p*32)*72 + kc0] = vreg[p];
        }
        __syncthreads();

        // prefetch next tile (T14: latency hides under MFMA+softmax)
        if (t + 1 < NT_ + 1) {
            const int nkt = (t + 1 >= n0) ? t + 1 - n0 : t + 1;
            #pragma unroll
            for (int p = 0; p < 2; ++p) {
                kreg[p] = *(const ush8*)&K [base  +
                    (size_t)(nkt*64 + r0 + p*32)*HD_ + kc0];
                vreg[p] = *(const ush8*)&Vt[vbase +
                    (size_t)(r0 + p*32)*S_ + nkt*64 + kc0];
            }
        }

        // S = Q K^T  (wave's 16 q-rows x 64 kv)
        f32x4 sac[4];
        #pragma unroll
        for (int nf = 0; nf < 4; ++nf) sac[nf] = z4;
        __builtin_amdgcn_s_setprio(1);
        #pragma unroll
        for (int nf = 0; nf < 4; ++nf)
            #pragma unroll
            for (int ks = 0; ks < 2; ++ks) {
                const bf16x8 kf =
                    *(const bf16x8*)&Ks[(nf*16 + cl)*72 + ks*32 + g*8];
                sac[nf] = __builtin_amdgcn_mfma_f32_16x16x32_bf16(
                    qf[ks], kf, sac[nf], 0, 0, 0);
            }
        __builtin_amdgcn_s_setprio(0);

        // online softmax; P -> LDS
        const bool diag = (kt == qt);
        #pragma unroll
        for (int r = 0; r < 4; ++r) {
            const int iloc = wave*16 + g*4 + r;
            float sv[4];
            #pragma unroll
            for (int nf = 0; nf < 4; ++nf) {
                sv[nf] = sac[nf][r];
                if (diag && (nf*16 + cl) > iloc) sv[nf] = -3.0e38f;
            }
            float mx = fmaxf(fmaxf(sv[0], sv[1]), fmaxf(sv[2], sv[3]));
            #pragma unroll
            for (int msk = 1; msk < 16; msk <<= 1)
                mx = fmaxf(mx, __shfl_xor(mx, msk));
            const float mnew = fmaxf(m_i[r], mx);
            const float es = __expf(m_i[r] - mnew);
            float ls = 0.f;
            float pv[4];
            #pragma unroll
            for (int nf = 0; nf < 4; ++nf) {
                pv[nf] = __expf(sv[nf] - mnew);
                ls += pv[nf];
            }
            #pragma unroll
            for (int msk = 1; msk < 16; msk <<= 1)
                ls += __shfl_xor(ls, msk);
            m_i[r] = mnew;
            l_i[r] = l_i[r] * es + ls;
            #pragma unroll
            for (int nf = 0; nf < 4; ++nf) {
                oac[nf][r] *= es;
                Ps[iloc*72 + nf*16 + cl] = f2b(pv[nf]);
            }
        }

        // O += P V  (Ps region is wave-private; lgkmcnt orders write->read)
        bf16x8 pa[2];
        #pragma unroll
        for (int ks = 0; ks < 2; ++ks)
            pa[ks] = *(const bf16x8*)&Ps[(wave*16 + cl)*72 + ks*32 + g*8];
        __builtin_amdgcn_s_setprio(1);
        #pragma unroll
        for (int nf = 0; nf < 4; ++nf)
            #pragma unroll
            for (int ks = 0; ks < 2; ++ks) {
                const bf16x8 vb =
                    *(const bf16x8*)&Vs[(nf*16 + cl)*72 + ks*32 + g*8];
                oac[nf] = __builtin_amdgcn_mfma_f32_16x16x32_bf16(
                    pa[ks], vb, oac[nf], 0, 0, 0);
            }
        __builtin_amdgcn_s_setprio(0);
        __syncthreads();
    }

    // part-1 epilogue
    #pragma unroll
    for (int r = 0; r < 4; ++r) {
        const float inv = 1.f / l_i[r];
        const int srow = qt*64 + wave*16 + g*4 + r;
        #pragma unroll
        for (int nf = 0; nf < 4; ++nf)
            out[(size_t)(b*S_ + srow)*D_ + h*HD_ + nf*16 + cl] =
                f2b(oac[nf][r] * inv);
    }
}

// ---------------------------------------------------------------------------
extern "C" void kernel_launch(void* const* d_in, const int* in_sizes, int n_in,
                              void* d_out, int out_size, void* d_ws, size_t ws_size,
                              hipStream_t stream)
{
    const float* x    = (const float*)d_in[0];
    const float* Wq_w = (const float*)d_in[1];
    const float* Wq_b = (const float*)d_in[2];
    const float* Wk_w = (const float*)d_in[3];
    const float* Wk_b = (const float*)d_in[4];
    const float* Wv_w = (const float*)d_in[5];
    const float* Wv_b = (const float*)d_in[6];
    const float* Wo_w = (const float*)d_in[7];
    const float* Wo_b = (const float*)d_in[8];
    float* out = (float*)d_out;

    u16* xb    = (u16*)d_ws;                       // [M_][D_] bf16
    u16* wqt   = xb  + (size_t)M_*D_;              // [N][K] bf16
    u16* wkt   = wqt + (size_t)D_*D_;
    u16* wvt   = wkt + (size_t)D_*D_;
    u16* wot   = wvt + (size_t)D_*D_;
    u16* q     = wot + (size_t)D_*D_;              // [B,H,S,HD]
    u16* k     = q   + (size_t)M_*D_;              // [B,H,S,HD]
    u16* vt    = k   + (size_t)M_*D_;              // [B,H,HD,S]
    u16* attnb = vt  + (size_t)M_*D_;              // [M_][D_]

    cast_f32_bf16<<<2048, 256, 0, stream>>>(x, xb, M_*D_/8);
    transpose_cast<<<dim3(16,16), 256, 0, stream>>>(Wq_w, wqt);
    transpose_cast<<<dim3(16,16), 256, 0, stream>>>(Wk_w, wkt);
    transpose_cast<<<dim3(16,16), 256, 0, stream>>>(Wv_w, wvt);
    transpose_cast<<<dim3(16,16), 256, 0, stream>>>(Wo_w, wot);

    gemm_qkv<<<dim3(M_/128, 24), 256, 0, stream>>>(
        xb, wqt, wkt, wvt, Wq_b, Wk_b, Wv_b, q, k, vt);

    attn_bf16<<<dim3(NT_/2, H_, B_), 256, 0, stream>>>(q, k, vt, attnb);

    gemm_oproj<<<dim3(M_/128, D_/128), 256, 0, stream>>>(attnb, wot, Wo_b, out);
}

// Round 6
// 299.000 us; speedup vs baseline: 1.6238x; 1.1406x over previous
//
#include <hip/hip_runtime.h>
#include <hip/hip_bf16.h>

// MHA B=4,S=2048,D=1024,H=16,HD=64 — bf16 MFMA pipeline, fp32 accum/softmax.
// v5 (resubmit): attn with swapped QK^T (S^T = K·Q^T) -> in-register softmax
// (per-lane q-row, 2 shfl reduce), P->PV B-frags via cvt_pk_bf16 + shfl,
// LDS double-buffer (1 barrier/tile), exp2-domain logits; gemm_qkv V^T
// epilogue through LDS (pitch 136 u16 = 16B-aligned rows).

#define B_  4
#define S_  2048
#define D_  1024
#define H_  16
#define HD_ 64
#define M_  (B_*S_)   // 8192
#define NT_ (S_/64)   // 32 kv/q tiles

typedef unsigned short u16;
typedef __attribute__((ext_vector_type(8))) short bf16x8;
typedef __attribute__((ext_vector_type(4))) float f32x4;
typedef __attribute__((ext_vector_type(8))) unsigned short ush8;
typedef __attribute__((ext_vector_type(4))) unsigned short ush4;

static __device__ __forceinline__ u16 f2b(float f) {
    unsigned int u = __float_as_uint(f);
    return (u16)((u + 0x7fffu + ((u >> 16) & 1u)) >> 16);
}

static __device__ __forceinline__ int cvt_pk_bf16(float a, float b) {
    int r;
    asm("v_cvt_pk_bf16_f32 %0, %1, %2" : "=v"(r) : "v"(a), "v"(b));
    return r;
}

#define EXP2(x) exp2f(x)

#define GLOAD_LDS16(g, l)                                                      \
    __builtin_amdgcn_global_load_lds(                                          \
        (const __attribute__((address_space(1))) void*)(g),                    \
        (__attribute__((address_space(3))) void*)(l), 16, 0, 0)

// ---------------------------------------------------------------------------
__global__ __launch_bounds__(256)
void cast_f32_bf16(const float* __restrict__ in, u16* __restrict__ out, int n8)
{
    int i = blockIdx.x * blockDim.x + threadIdx.x;
    const int stride = gridDim.x * blockDim.x;
    for (; i < n8; i += stride) {
        const float4 a = ((const float4*)in)[i*2+0];
        const float4 b = ((const float4*)in)[i*2+1];
        ush8 o;
        o[0]=f2b(a.x); o[1]=f2b(a.y); o[2]=f2b(a.z); o[3]=f2b(a.w);
        o[4]=f2b(b.x); o[5]=f2b(b.y); o[6]=f2b(b.z); o[7]=f2b(b.w);
        ((ush8*)out)[i] = o;
    }
}

// ---------------------------------------------------------------------------
// W [K][N] fp32 -> Wt [N][K] bf16 (64x64 tiles)
// ---------------------------------------------------------------------------
__global__ __launch_bounds__(256)
void transpose_cast(const float* __restrict__ W, u16* __restrict__ Wt)
{
    __shared__ u16 T[64*72];
    const int tid = threadIdx.x;
    const int k0 = blockIdx.x * 64, n0 = blockIdx.y * 64;
    #pragma unroll
    for (int it = 0; it < 4; ++it) {
        const int li = tid + it*256;
        const int kk = li >> 4;
        const int nc = (li & 15) * 4;
        const float4 w4 = *(const float4*)&W[(size_t)(k0+kk)*D_ + n0 + nc];
        T[(nc+0)*72 + kk] = f2b(w4.x);
        T[(nc+1)*72 + kk] = f2b(w4.y);
        T[(nc+2)*72 + kk] = f2b(w4.z);
        T[(nc+3)*72 + kk] = f2b(w4.w);
    }
    __syncthreads();
    #pragma unroll
    for (int it = 0; it < 2; ++it) {
        const int li = tid + it*256;
        const int nr = li >> 3;
        const int kc = (li & 7) * 8;
        const ush8 v = *(const ush8*)&T[nr*72 + kc];
        *(ush8*)&Wt[(size_t)(n0+nr)*D_ + k0 + kc] = v;
    }
}

// ---------------------------------------------------------------------------
// Fused QKV GEMM. sel = blockIdx.y>>3: 0=Q (scaled, [b,h,s,d]),
// 1=K ([b,h,s,d]), 2=V (transposed out [b,h,d,s] via LDS epilogue).
// 128x128 tile, BK=32, 4 waves, 16x16x32 bf16 MFMA.
// Q scale folds 1/sqrt(64) and log2(e) (attn uses exp2-domain softmax).
// ---------------------------------------------------------------------------
#define QSCALE 0.18033688f   // 0.125 * log2(e)
#define TP_ 136              // V^T LDS tile pitch (u16): 272B, 16B-aligned

__global__ __launch_bounds__(256)
void gemm_qkv(const u16* __restrict__ A,
              const u16* __restrict__ wq, const u16* __restrict__ wk,
              const u16* __restrict__ wv,
              const float* __restrict__ bq, const float* __restrict__ bk,
              const float* __restrict__ bv,
              u16* __restrict__ oq, u16* __restrict__ ok, u16* __restrict__ ovt)
{
    __shared__ u16 sh[64*TP_];         // As[4096] | Bs[4096]; reused as T[64][TP_]
    u16* As = sh;
    u16* Bs = sh + 4096;

    const int tid  = threadIdx.x;
    const int lane = tid & 63;
    const int wave = tid >> 6;
    const int wr = wave >> 1, wc = wave & 1;
    const int bm = blockIdx.x * 128;
    const int sel = blockIdx.y >> 3;
    const int bn = (blockIdx.y & 7) * 128;
    const u16* Bt = sel == 0 ? wq : sel == 1 ? wk : wv;
    const float* bias = sel == 0 ? bq : sel == 1 ? bk : bv;

    const int srow = wave*32 + (lane >> 2);
    const int sk   = (lane & 3) * 8;
    const u16* gA0 = A  + (size_t)(bm + srow)      * D_ + sk;
    const u16* gA1 = A  + (size_t)(bm + srow + 16) * D_ + sk;
    const u16* gB0 = Bt + (size_t)(bn + srow)      * D_ + sk;
    const u16* gB1 = Bt + (size_t)(bn + srow + 16) * D_ + sk;
    u16* lA0 = &As[(wave*2+0)*512];
    u16* lA1 = &As[(wave*2+1)*512];
    u16* lB0 = &Bs[(wave*2+0)*512];
    u16* lB1 = &Bs[(wave*2+1)*512];

    const f32x4 z4 = {0.f, 0.f, 0.f, 0.f};
    f32x4 acc[4][4];
    #pragma unroll
    for (int i = 0; i < 4; ++i)
        #pragma unroll
        for (int j = 0; j < 4; ++j) acc[i][j] = z4;

    const int cl = lane & 15;
    const int g  = lane >> 4;

    for (int k0 = 0; k0 < D_; k0 += 32) {
        GLOAD_LDS16(gA0 + k0, lA0);
        GLOAD_LDS16(gA1 + k0, lA1);
        GLOAD_LDS16(gB0 + k0, lB0);
        GLOAD_LDS16(gB1 + k0, lB1);
        __syncthreads();

        bf16x8 af[4], bfv[4];
        #pragma unroll
        for (int mf = 0; mf < 4; ++mf)
            af[mf] = *(const bf16x8*)&As[(wr*64 + mf*16 + cl)*32 + g*8];
        #pragma unroll
        for (int nf = 0; nf < 4; ++nf)
            bfv[nf] = *(const bf16x8*)&Bs[(wc*64 + nf*16 + cl)*32 + g*8];
        __builtin_amdgcn_s_setprio(1);
        #pragma unroll
        for (int mf = 0; mf < 4; ++mf)
            #pragma unroll
            for (int nf = 0; nf < 4; ++nf)
                acc[mf][nf] = __builtin_amdgcn_mfma_f32_16x16x32_bf16(
                    af[mf], bfv[nf], acc[mf][nf], 0, 0, 0);
        __builtin_amdgcn_s_setprio(0);
        __syncthreads();
    }

    if (sel == 2) {
        // V: transpose via LDS, write [b,h,d,s] with 256B-coalesced rows.
        const int b = bm >> 11, s0 = bm & (S_-1);
        u16* T = sh;
        #pragma unroll
        for (int hh = 0; hh < 2; ++hh) {
            if (wc == hh) {
                #pragma unroll
                for (int nf = 0; nf < 4; ++nf) {
                    const float bvv = bias[bn + wc*64 + nf*16 + cl];
                    #pragma unroll
                    for (int mf = 0; mf < 4; ++mf) {
                        ush4 o4;
                        #pragma unroll
                        for (int r = 0; r < 4; ++r)
                            o4[r] = f2b(acc[mf][nf][r] + bvv);
                        *(ush4*)&T[(nf*16 + cl)*TP_ + wr*64 + mf*16 + g*4] = o4;
                    }
                }
            }
            __syncthreads();
            const int h = (bn >> 6) + hh;
            #pragma unroll
            for (int pp = 0; pp < 4; ++pp) {
                const int d = wave*16 + pp*4 + g;
                const ush8 vv = *(const ush8*)&T[d*TP_ + cl*8];
                *(ush8*)&ovt[((size_t)((b*H_ + h)*HD_ + d))*S_ + s0 + cl*8] = vv;
            }
            __syncthreads();
        }
    } else {
        const float oscale = sel == 0 ? QSCALE : 1.0f;
        u16* o = sel == 0 ? oq : ok;
        #pragma unroll
        for (int nf = 0; nf < 4; ++nf) {
            const int col = bn + wc*64 + nf*16 + cl;
            const float bvv = bias[col];
            const int h = col >> 6, d = col & (HD_-1);
            #pragma unroll
            for (int mf = 0; mf < 4; ++mf) {
                #pragma unroll
                for (int r = 0; r < 4; ++r) {
                    const int row = bm + wr*64 + mf*16 + g*4 + r;
                    const float v = (acc[mf][nf][r] + bvv) * oscale;
                    const int bb = row >> 11, s = row & (S_-1);
                    o[((size_t)(bb*H_ + h)*S_ + s)*HD_ + d] = f2b(v);
                }
            }
        }
    }
}

// ---------------------------------------------------------------------------
// O-proj GEMM: fp32 out, row-major.
// ---------------------------------------------------------------------------
__global__ __launch_bounds__(256)
void gemm_oproj(const u16* __restrict__ A, const u16* __restrict__ Bt,
                const float* __restrict__ bias, float* __restrict__ out)
{
    __shared__ u16 As[128*32];
    __shared__ u16 Bs[128*32];
    const int tid  = threadIdx.x;
    const int lane = tid & 63;
    const int wave = tid >> 6;
    const int wr = wave >> 1, wc = wave & 1;
    const int bm = blockIdx.x * 128, bn = blockIdx.y * 128;

    const int srow = wave*32 + (lane >> 2);
    const int sk   = (lane & 3) * 8;
    const u16* gA0 = A  + (size_t)(bm + srow)      * D_ + sk;
    const u16* gA1 = A  + (size_t)(bm + srow + 16) * D_ + sk;
    const u16* gB0 = Bt + (size_t)(bn + srow)      * D_ + sk;
    const u16* gB1 = Bt + (size_t)(bn + srow + 16) * D_ + sk;
    u16* lA0 = &As[(wave*2+0)*512];
    u16* lA1 = &As[(wave*2+1)*512];
    u16* lB0 = &Bs[(wave*2+0)*512];
    u16* lB1 = &Bs[(wave*2+1)*512];

    const f32x4 z4 = {0.f, 0.f, 0.f, 0.f};
    f32x4 acc[4][4];
    #pragma unroll
    for (int i = 0; i < 4; ++i)
        #pragma unroll
        for (int j = 0; j < 4; ++j) acc[i][j] = z4;

    const int cl = lane & 15;
    const int g  = lane >> 4;

    for (int k0 = 0; k0 < D_; k0 += 32) {
        GLOAD_LDS16(gA0 + k0, lA0);
        GLOAD_LDS16(gA1 + k0, lA1);
        GLOAD_LDS16(gB0 + k0, lB0);
        GLOAD_LDS16(gB1 + k0, lB1);
        __syncthreads();

        bf16x8 af[4], bfv[4];
        #pragma unroll
        for (int mf = 0; mf < 4; ++mf)
            af[mf] = *(const bf16x8*)&As[(wr*64 + mf*16 + cl)*32 + g*8];
        #pragma unroll
        for (int nf = 0; nf < 4; ++nf)
            bfv[nf] = *(const bf16x8*)&Bs[(wc*64 + nf*16 + cl)*32 + g*8];
        __builtin_amdgcn_s_setprio(1);
        #pragma unroll
        for (int mf = 0; mf < 4; ++mf)
            #pragma unroll
            for (int nf = 0; nf < 4; ++nf)
                acc[mf][nf] = __builtin_amdgcn_mfma_f32_16x16x32_bf16(
                    af[mf], bfv[nf], acc[mf][nf], 0, 0, 0);
        __builtin_amdgcn_s_setprio(0);
        __syncthreads();
    }

    #pragma unroll
    for (int nf = 0; nf < 4; ++nf) {
        const int col = bn + wc*64 + nf*16 + cl;
        const float bvv = bias[col];
        #pragma unroll
        for (int mf = 0; mf < 4; ++mf) {
            #pragma unroll
            for (int r = 0; r < 4; ++r) {
                const int row = bm + wr*64 + mf*16 + g*4 + r;
                out[(size_t)row*D_ + col] = acc[mf][nf][r] + bvv;
            }
        }
    }
}

// ---------------------------------------------------------------------------
// Flash attention (causal), swapped-QK^T in-register softmax.
// Triangle pairing: block does q-tiles `pair` and `31-pair` (33 units).
// 4 waves x 16 q-rows; kv tiles of 64. Q,K: [b,h,s,d]; V pre-transposed
// [b,h,d,s]. LDS double-buffered, chunk-XOR swizzle, 1 barrier/tile.
// S^T = mfma(K, Q): lane owns q = cl, kv = nf*16 + g*4 + r (16 values).
// Softmax per-lane + shfl_xor(16,32). P -> PV B-frags via cvt_pk + shfl.
// PV: O^T = mfma(V^T, P^T): lane owns q = cl, d = nf*16 + g*4 + r.
// Logits in exp2 domain (Q pre-scaled by 0.125*log2e).
// ---------------------------------------------------------------------------
__global__ __launch_bounds__(256, 4)
void attn_bf16(const u16* __restrict__ Q, const u16* __restrict__ K,
               const u16* __restrict__ Vt, u16* __restrict__ out)
{
    __shared__ u16 Ks[2][64*64];
    __shared__ u16 Vs[2][64*64];

    const int tid  = threadIdx.x;
    const int lane = tid & 63;
    const int wave = tid >> 6;
    const int cl = lane & 15;
    const int g  = lane >> 4;
    const int swz = cl & 7;            // row&7 for frag reads (rows nf*16+cl)
    const int pair = blockIdx.x, h = blockIdx.y, b = blockIdx.z;
    const size_t base  = ((size_t)(b*H_ + h)) * S_ * HD_;   // Q,K: [s][d]
    const size_t vbase = ((size_t)(b*H_ + h)) * HD_ * S_;   // Vt: [d][s]

    int qt = pair;
    const int n0 = pair + 1;           // tiles in part 0; total = 33

    // staging coords: thread stages rows r0, r0+32; chunk c0 (8 elems)
    const int r0 = tid >> 3;
    const int c0 = tid & 7;

    // Q B-frags for part 0
    bf16x8 qf[2];
    #pragma unroll
    for (int ks = 0; ks < 2; ++ks)
        qf[ks] = *(const bf16x8*)&Q[base +
            (size_t)(qt*64 + wave*16 + cl)*HD_ + ks*32 + g*8];

    // prefetch kv tile 0
    ush8 kreg[2], vreg[2];
    #pragma unroll
    for (int p = 0; p < 2; ++p) {
        kreg[p] = *(const ush8*)&K [base  + (size_t)(r0 + p*32)*HD_ + c0*8];
        vreg[p] = *(const ush8*)&Vt[vbase + (size_t)(r0 + p*32)*S_  + c0*8];
    }

    const f32x4 z4 = {0.f, 0.f, 0.f, 0.f};
    f32x4 oac[4];
    float m_i = -3.0e38f, l_i = 0.f;
    #pragma unroll
    for (int nf = 0; nf < 4; ++nf) oac[nf] = z4;

    int cur = 0;
    for (int t = 0; t < NT_ + 1; ++t) {
        const int kt = (t >= n0) ? t - n0 : t;

        if (t == n0) {
            // part-0 epilogue, reinit for part 1
            const float inv = 1.f / l_i;
            const int srow = qt*64 + wave*16 + cl;
            #pragma unroll
            for (int nf = 0; nf < 4; ++nf) {
                ush4 o4;
                #pragma unroll
                for (int r = 0; r < 4; ++r) o4[r] = f2b(oac[nf][r] * inv);
                *(ush4*)&out[(size_t)(b*S_ + srow)*D_ + h*HD_ + nf*16 + g*4] = o4;
            }
            qt = NT_ - 1 - pair;
            #pragma unroll
            for (int ks = 0; ks < 2; ++ks)
                qf[ks] = *(const bf16x8*)&Q[base +
                    (size_t)(qt*64 + wave*16 + cl)*HD_ + ks*32 + g*8];
            m_i = -3.0e38f; l_i = 0.f;
            #pragma unroll
            for (int nf = 0; nf < 4; ++nf) oac[nf] = z4;
        }

        // commit prefetched tile (chunk-XOR swizzle: data chunk c at slot c^row&7)
        #pragma unroll
        for (int p = 0; p < 2; ++p) {
            const int row = r0 + p*32;
            const int slot = (c0 ^ (row & 7)) * 8;
            *(ush8*)&Ks[cur][row*64 + slot] = kreg[p];
            *(ush8*)&Vs[cur][row*64 + slot] = vreg[p];
        }
        __syncthreads();

        // prefetch next tile (global loads in flight across compute)
        if (t + 1 < NT_ + 1) {
            const int nkt = (t + 1 >= n0) ? t + 1 - n0 : t + 1;
            #pragma unroll
            for (int p = 0; p < 2; ++p) {
                kreg[p] = *(const ush8*)&K [base  +
                    (size_t)(nkt*64 + r0 + p*32)*HD_ + c0*8];
                vreg[p] = *(const ush8*)&Vt[vbase +
                    (size_t)(r0 + p*32)*S_ + nkt*64 + c0*8];
            }
        }

        // S^T = K·Q^T : sac[nf][r] = S[kv = nf*16+g*4+r][q = cl]
        f32x4 sac[4];
        #pragma unroll
        for (int nf = 0; nf < 4; ++nf) sac[nf] = z4;
        __builtin_amdgcn_s_setprio(1);
        #pragma unroll
        for (int ks = 0; ks < 2; ++ks) {
            const int slot = ((ks*4 + g) ^ swz) * 8;
            #pragma unroll
            for (int nf = 0; nf < 4; ++nf) {
                const bf16x8 kf =
                    *(const bf16x8*)&Ks[cur][(nf*16 + cl)*64 + slot];
                sac[nf] = __builtin_amdgcn_mfma_f32_16x16x32_bf16(
                    kf, qf[ks], sac[nf], 0, 0, 0);
            }
        }
        __builtin_amdgcn_s_setprio(0);

        // causal mask (diag tile only)
        if (kt == qt) {
            const int qloc = wave*16 + cl;
            #pragma unroll
            for (int nf = 0; nf < 4; ++nf)
                #pragma unroll
                for (int r = 0; r < 4; ++r)
                    if (nf*16 + g*4 + r > qloc) sac[nf][r] = -3.0e38f;
        }

        // in-register online softmax (exp2 domain), q = cl per lane
        float mx = -3.0e38f;
        #pragma unroll
        for (int nf = 0; nf < 4; ++nf)
            #pragma unroll
            for (int r = 0; r < 4; ++r) mx = fmaxf(mx, sac[nf][r]);
        mx = fmaxf(mx, __shfl_xor(mx, 16));
        mx = fmaxf(mx, __shfl_xor(mx, 32));
        const float mnew = fmaxf(m_i, mx);
        const float es = EXP2(m_i - mnew);
        float ls = 0.f;
        #pragma unroll
        for (int nf = 0; nf < 4; ++nf) {
            float s0 = EXP2(sac[nf][0] - mnew);
            float s1 = EXP2(sac[nf][1] - mnew);
            float s2 = EXP2(sac[nf][2] - mnew);
            float s3 = EXP2(sac[nf][3] - mnew);
            sac[nf][0] = s0; sac[nf][1] = s1; sac[nf][2] = s2; sac[nf][3] = s3;
            ls += (s0 + s1) + (s2 + s3);
        }
        ls += __shfl_xor(ls, 16);
        ls += __shfl_xor(ls, 32);
        m_i = mnew;
        l_i = l_i * es + ls;
        #pragma unroll
        for (int nf = 0; nf < 4; ++nf)
            #pragma unroll
            for (int r = 0; r < 4; ++r) oac[nf][r] *= es;

        // pack P rows to bf16 pairs
        int X[4], Y[4];
        #pragma unroll
        for (int nf = 0; nf < 4; ++nf) {
            X[nf] = cvt_pk_bf16(sac[nf][0], sac[nf][1]);
            Y[nf] = cvt_pk_bf16(sac[nf][2], sac[nf][3]);
        }

        // build PV B-frags: lane (cl,g) needs P^T[kv=ks*32+g*8+j][q=cl]
        // src lane = cl + 32*(g&1) (+16 for j>=4); src block nf = 2ks + (g>>1)
        const int sA = cl + ((g & 1) << 5);
        const bool hi = (g >> 1) != 0;
        __builtin_amdgcn_s_setprio(1);
        #pragma unroll
        for (int ks = 0; ks < 2; ++ks) {
            const int x0 = __shfl(X[2*ks],   sA);
            const int x1 = __shfl(X[2*ks+1], sA);
            const int y0 = __shfl(Y[2*ks],   sA);
            const int y1 = __shfl(Y[2*ks+1], sA);
            const int x2 = __shfl(X[2*ks],   sA + 16);
            const int x3 = __shfl(X[2*ks+1], sA + 16);
            const int y2 = __shfl(Y[2*ks],   sA + 16);
            const int y3 = __shfl(Y[2*ks+1], sA + 16);
            int4 w;
            w.x = hi ? x1 : x0;
            w.y = hi ? y1 : y0;
            w.z = hi ? x3 : x2;
            w.w = hi ? y3 : y2;
            const bf16x8 pb = __builtin_bit_cast(bf16x8, w);
            const int slot = ((ks*4 + g) ^ swz) * 8;
            #pragma unroll
            for (int nfd = 0; nfd < 4; ++nfd) {
                const bf16x8 vf =
                    *(const bf16x8*)&Vs[cur][(nfd*16 + cl)*64 + slot];
                oac[nfd] = __builtin_amdgcn_mfma_f32_16x16x32_bf16(
                    vf, pb, oac[nfd], 0, 0, 0);
            }
        }
        __builtin_amdgcn_s_setprio(0);
        cur ^= 1;
    }

    // part-1 epilogue
    {
        const float inv = 1.f / l_i;
        const int srow = qt*64 + wave*16 + cl;
        #pragma unroll
        for (int nf = 0; nf < 4; ++nf) {
            ush4 o4;
            #pragma unroll
            for (int r = 0; r < 4; ++r) o4[r] = f2b(oac[nf][r] * inv);
            *(ush4*)&out[(size_t)(b*S_ + srow)*D_ + h*HD_ + nf*16 + g*4] = o4;
        }
    }
}

// ---------------------------------------------------------------------------
extern "C" void kernel_launch(void* const* d_in, const int* in_sizes, int n_in,
                              void* d_out, int out_size, void* d_ws, size_t ws_size,
                              hipStream_t stream)
{
    const float* x    = (const float*)d_in[0];
    const float* Wq_w = (const float*)d_in[1];
    const float* Wq_b = (const float*)d_in[2];
    const float* Wk_w = (const float*)d_in[3];
    const float* Wk_b = (const float*)d_in[4];
    const float* Wv_w = (const float*)d_in[5];
    const float* Wv_b = (const float*)d_in[6];
    const float* Wo_w = (const float*)d_in[7];
    const float* Wo_b = (const float*)d_in[8];
    float* out = (float*)d_out;

    u16* xb    = (u16*)d_ws;                       // [M_][D_] bf16
    u16* wqt   = xb  + (size_t)M_*D_;              // [N][K] bf16
    u16* wkt   = wqt + (size_t)D_*D_;
    u16* wvt   = wkt + (size_t)D_*D_;
    u16* wot   = wvt + (size_t)D_*D_;
    u16* q     = wot + (size_t)D_*D_;              // [B,H,S,HD]
    u16* k     = q   + (size_t)M_*D_;              // [B,H,S,HD]
    u16* vt    = k   + (size_t)M_*D_;              // [B,H,HD,S]
    u16* attnb = vt  + (size_t)M_*D_;              // [M_][D_]

    cast_f32_bf16<<<2048, 256, 0, stream>>>(x, xb, M_*D_/8);
    transpose_cast<<<dim3(16,16), 256, 0, stream>>>(Wq_w, wqt);
    transpose_cast<<<dim3(16,16), 256, 0, stream>>>(Wk_w, wkt);
    transpose_cast<<<dim3(16,16), 256, 0, stream>>>(Wv_w, wvt);
    transpose_cast<<<dim3(16,16), 256, 0, stream>>>(Wo_w, wot);

    gemm_qkv<<<dim3(M_/128, 24), 256, 0, stream>>>(
        xb, wqt, wkt, wvt, Wq_b, Wk_b, Wv_b, q, k, vt);

    attn_bf16<<<dim3(NT_/2, H_, B_), 256, 0, stream>>>(q, k, vt, attnb);

    gemm_oproj<<<dim3(M_/128, D_/128), 256, 0, stream>>>(attnb, wot, Wo_b, out);
}

// Round 7
// 293.680 us; speedup vs baseline: 1.6532x; 1.0181x over previous
//
#include <hip/hip_runtime.h>
#include <hip/hip_bf16.h>

// MHA B=4,S=2048,D=1024,H=16,HD=64 — bf16 MFMA pipeline, fp32 accum/softmax.
// v6: GEMMs rewritten as 256x256/BK=64/8-wave 4-phase schedule (raw barriers,
// counted-drain vmcnt(0) once per K-tile, chunk-XOR LDS swizzle via
// pre-swizzled global source + swizzled ds_read). Attn unchanged from v5.

#define B_  4
#define S_  2048
#define D_  1024
#define H_  16
#define HD_ 64
#define M_  (B_*S_)   // 8192
#define NT_ (S_/64)   // 32 kv/q tiles

typedef unsigned short u16;
typedef __attribute__((ext_vector_type(8))) short bf16x8;
typedef __attribute__((ext_vector_type(4))) float f32x4;
typedef __attribute__((ext_vector_type(8))) unsigned short ush8;
typedef __attribute__((ext_vector_type(4))) unsigned short ush4;

static __device__ __forceinline__ u16 f2b(float f) {
    unsigned int u = __float_as_uint(f);
    return (u16)((u + 0x7fffu + ((u >> 16) & 1u)) >> 16);
}

static __device__ __forceinline__ int cvt_pk_bf16(float a, float b) {
    int r;
    asm("v_cvt_pk_bf16_f32 %0, %1, %2" : "=v"(r) : "v"(a), "v"(b));
    return r;
}

#define EXP2(x) exp2f(x)

#define GLOAD_LDS16(g, l)                                                      \
    __builtin_amdgcn_global_load_lds(                                          \
        (const __attribute__((address_space(1))) void*)(g),                    \
        (__attribute__((address_space(3))) void*)(l), 16, 0, 0)

#define QSCALE 0.18033688f   // 0.125 * log2(e)

// ---------------------------------------------------------------------------
__global__ __launch_bounds__(256)
void cast_f32_bf16(const float* __restrict__ in, u16* __restrict__ out, int n8)
{
    int i = blockIdx.x * blockDim.x + threadIdx.x;
    const int stride = gridDim.x * blockDim.x;
    for (; i < n8; i += stride) {
        const float4 a = ((const float4*)in)[i*2+0];
        const float4 b = ((const float4*)in)[i*2+1];
        ush8 o;
        o[0]=f2b(a.x); o[1]=f2b(a.y); o[2]=f2b(a.z); o[3]=f2b(a.w);
        o[4]=f2b(b.x); o[5]=f2b(b.y); o[6]=f2b(b.z); o[7]=f2b(b.w);
        ((ush8*)out)[i] = o;
    }
}

// ---------------------------------------------------------------------------
// W [K][N] fp32 -> Wt [N][K] bf16 (64x64 tiles)
// ---------------------------------------------------------------------------
__global__ __launch_bounds__(256)
void transpose_cast(const float* __restrict__ W, u16* __restrict__ Wt)
{
    __shared__ u16 T[64*72];
    const int tid = threadIdx.x;
    const int k0 = blockIdx.x * 64, n0 = blockIdx.y * 64;
    #pragma unroll
    for (int it = 0; it < 4; ++it) {
        const int li = tid + it*256;
        const int kk = li >> 4;
        const int nc = (li & 15) * 4;
        const float4 w4 = *(const float4*)&W[(size_t)(k0+kk)*D_ + n0 + nc];
        T[(nc+0)*72 + kk] = f2b(w4.x);
        T[(nc+1)*72 + kk] = f2b(w4.y);
        T[(nc+2)*72 + kk] = f2b(w4.z);
        T[(nc+3)*72 + kk] = f2b(w4.w);
    }
    __syncthreads();
    #pragma unroll
    for (int it = 0; it < 2; ++it) {
        const int li = tid + it*256;
        const int nr = li >> 3;
        const int kc = (li & 7) * 8;
        const ush8 v = *(const ush8*)&T[nr*72 + kc];
        *(ush8*)&Wt[(size_t)(n0+nr)*D_ + k0 + kc] = v;
    }
}

// ---------------------------------------------------------------------------
// 256x256 GEMM core: C = A[256 rows @arow0][K=1024] * Bt[256 rows @brow0][K]^T
// BK=64, 8 waves (2M x 4N), per-wave 128x64 = acc[8][4] frags.
// LDS: A/B double-buffered [2][256*64] u16 each (128KB total in sh[0..65535]).
// Swizzle: 16B chunk c of row r stored at slot c^(r&7); gload_lds dest is
// linear so the SOURCE is pre-swizzled; ds_read uses swizzled slot.
// Schedule per K-tile: 4 phases {ds_read frags | stage next-tile halves
// (p0:A, p1:B) | raw barrier | setprio MFMA} ; vmcnt(0) drain at p3 only.
// ---------------------------------------------------------------------------
__device__ __forceinline__ void gemm256_loop(
    const u16* __restrict__ Ag, size_t arow0,
    const u16* __restrict__ Bg, size_t brow0,
    u16* __restrict__ sh, f32x4 (&acc)[8][4])
{
    const int tid  = threadIdx.x;
    const int lane = tid & 63;
    const int wave = tid >> 6;
    const int wr = wave >> 2, wc = wave & 3;
    const int cl = lane & 15, g = lane >> 4;
    const int sw = cl & 7;
    u16* const Ab = sh;
    u16* const Bb = sh + 32768;

    const int srow   = lane >> 3;              // 0..7 within an 8-row segment
    const int schunk = (lane & 7) ^ srow;      // pre-swizzled source chunk

    auto stage_half = [&](const u16* gbase, size_t row0, int k0, u16* lbase) {
        #pragma unroll
        for (int i = 0; i < 2; ++i) {
            const int seg = wave*2 + i;        // 0..15 (8 rows each)
            const u16* src = gbase + (row0 + seg*8 + srow) * (size_t)D_
                                   + k0 + schunk*8;
            u16* dst = lbase + seg*512;        // wave-uniform; lane adds 16B
            GLOAD_LDS16(src, dst);
        }
    };

    // prologue: tile 0 -> buffer 0
    stage_half(Ag, arow0,       0, Ab);
    stage_half(Ag, arow0 + 128, 0, Ab + 8192);
    stage_half(Bg, brow0,       0, Bb);
    stage_half(Bg, brow0 + 128, 0, Bb + 8192);
    __syncthreads();

    for (int t = 0; t < 16; ++t) {
        u16* const Ac = Ab + (t & 1) * 16384;
        u16* const Bc = Bb + (t & 1) * 16384;
        u16* const An = Ab + ((t + 1) & 1) * 16384;
        u16* const Bn = Bb + ((t + 1) & 1) * 16384;
        const int  kn   = (t + 1) * 64;
        const bool more = (t < 15);

        // B-frags hoisted for the whole tile (8 x ds_read_b128)
        bf16x8 bfr[4][2];
        #pragma unroll
        for (int nf = 0; nf < 4; ++nf)
            #pragma unroll
            for (int ks = 0; ks < 2; ++ks)
                bfr[nf][ks] = *(const bf16x8*)
                    &Bc[(wc*64 + nf*16 + cl)*64 + (((ks*4 + g) ^ sw) * 8)];

        #pragma unroll
        for (int p = 0; p < 4; ++p) {
            bf16x8 af[2][2];
            #pragma unroll
            for (int e = 0; e < 2; ++e)
                #pragma unroll
                for (int ks = 0; ks < 2; ++ks)
                    af[e][ks] = *(const bf16x8*)
                        &Ac[(wr*128 + (p*2 + e)*16 + cl)*64
                            + (((ks*4 + g) ^ sw) * 8)];

            if (p == 0 && more) {          // stage next tile's A halves
                stage_half(Ag, arow0,       kn, An);
                stage_half(Ag, arow0 + 128, kn, An + 8192);
            } else if (p == 1 && more) {   // stage next tile's B halves
                stage_half(Bg, brow0,       kn, Bn);
                stage_half(Bg, brow0 + 128, kn, Bn + 8192);
            }

            __builtin_amdgcn_sched_barrier(0);
            __builtin_amdgcn_s_barrier();
            __builtin_amdgcn_sched_barrier(0);

            __builtin_amdgcn_s_setprio(1);
            #pragma unroll
            for (int e = 0; e < 2; ++e)
                #pragma unroll
                for (int ks = 0; ks < 2; ++ks)
                    #pragma unroll
                    for (int nf = 0; nf < 4; ++nf)
                        acc[p*2 + e][nf] = __builtin_amdgcn_mfma_f32_16x16x32_bf16(
                            af[e][ks], bfr[nf][ks], acc[p*2 + e][nf], 0, 0, 0);
            __builtin_amdgcn_s_setprio(0);

            if (p == 3) {   // drain next-tile stages once per K-tile
                asm volatile("s_waitcnt vmcnt(0)" ::: "memory");
            }
            __builtin_amdgcn_sched_barrier(0);
            __builtin_amdgcn_s_barrier();
            __builtin_amdgcn_sched_barrier(0);
        }
    }
    __syncthreads();
}

// ---------------------------------------------------------------------------
// Fused QKV GEMM, 256x256. blockIdx.y: sel = by>>2 (0=Q,1=K,2=V), bn=(by&3)*256.
// Q/K: bf16 head-permuted [b,h,s,d] (Q scaled QSCALE). V: transposed out
// [b,h,d,s] via LDS re-transpose (4 heads/block).
// ---------------------------------------------------------------------------
__global__ __launch_bounds__(512, 2)
void gemm_qkv256(const u16* __restrict__ A,
                 const u16* __restrict__ wq, const u16* __restrict__ wk,
                 const u16* __restrict__ wv,
                 const float* __restrict__ bq, const float* __restrict__ bk,
                 const float* __restrict__ bv,
                 u16* __restrict__ oq, u16* __restrict__ ok,
                 u16* __restrict__ ovt)
{
    __shared__ u16 sh[67584];   // 128KB GEMM bufs; reused: 4x [64][264] V^T tiles

    const int tid  = threadIdx.x;
    const int lane = tid & 63;
    const int wave = tid >> 6;
    const int wr = wave >> 2, wc = wave & 3;
    const int cl = lane & 15, g = lane >> 4;
    const size_t bm = (size_t)blockIdx.x * 256;
    const int by   = blockIdx.y;
    const int sel  = by >> 2;
    const int bn2  = (by & 3) * 256;
    const u16* Bt = sel == 0 ? wq : sel == 1 ? wk : wv;
    const float* bias = sel == 0 ? bq : sel == 1 ? bk : bv;

    f32x4 acc[8][4];
    const f32x4 z4 = {0.f, 0.f, 0.f, 0.f};
    #pragma unroll
    for (int i = 0; i < 8; ++i)
        #pragma unroll
        for (int j = 0; j < 4; ++j) acc[i][j] = z4;

    gemm256_loop(A, bm, Bt, (size_t)bn2, sh, acc);

    if (sel == 2) {
        // V: transpose 256x256 through LDS, write [b,h,d,s] coalesced.
        const int b  = (int)(bm >> 11);
        const int s0 = (int)(bm & (S_ - 1));
        #pragma unroll
        for (int nf = 0; nf < 4; ++nf) {
            const float bvv = bias[bn2 + wc*64 + nf*16 + cl];
            #pragma unroll
            for (int mf = 0; mf < 8; ++mf) {
                ush4 o4;
                #pragma unroll
                for (int r = 0; r < 4; ++r) o4[r] = f2b(acc[mf][nf][r] + bvv);
                *(ush4*)&sh[wc*16896 + (nf*16 + cl)*264 + wr*128 + mf*16 + g*4] = o4;
            }
        }
        __syncthreads();
        const int head = wave >> 1, shalf = wave & 1;
        const int hh = (bn2 >> 6) + head;
        #pragma unroll
        for (int it = 0; it < 16; ++it) {
            const int lin = it*64 + lane;
            const int d = lin >> 4, sc = lin & 15;
            const ush8 vv = *(const ush8*)&sh[head*16896 + d*264 + shalf*128 + sc*8];
            *(ush8*)&ovt[((size_t)((b*H_ + hh)*HD_ + d))*S_ + s0 + shalf*128 + sc*8] = vv;
        }
    } else {
        const float osc = sel == 0 ? QSCALE : 1.0f;
        u16* o = sel == 0 ? oq : ok;
        #pragma unroll
        for (int nf = 0; nf < 4; ++nf) {
            const int col = bn2 + wc*64 + nf*16 + cl;
            const float bvv = bias[col];
            const int h = col >> 6, d = col & (HD_ - 1);
            #pragma unroll
            for (int mf = 0; mf < 8; ++mf) {
                #pragma unroll
                for (int r = 0; r < 4; ++r) {
                    const size_t row = bm + wr*128 + mf*16 + g*4 + r;
                    const int bb = (int)(row >> 11), s = (int)(row & (S_ - 1));
                    o[((size_t)(bb*H_ + h)*S_ + s)*HD_ + d] =
                        f2b((acc[mf][nf][r] + bvv) * osc);
                }
            }
        }
    }
}

// ---------------------------------------------------------------------------
// O-proj GEMM, 256x256, fp32 row-major out.
// ---------------------------------------------------------------------------
__global__ __launch_bounds__(512, 2)
void gemm_oproj256(const u16* __restrict__ A, const u16* __restrict__ Bt,
                   const float* __restrict__ bias, float* __restrict__ out)
{
    __shared__ u16 sh[65536];

    const int tid  = threadIdx.x;
    const int lane = tid & 63;
    const int wave = tid >> 6;
    const int wr = wave >> 2, wc = wave & 3;
    const int cl = lane & 15, g = lane >> 4;
    const size_t bm = (size_t)blockIdx.x * 256;
    const size_t bn = (size_t)blockIdx.y * 256;

    f32x4 acc[8][4];
    const f32x4 z4 = {0.f, 0.f, 0.f, 0.f};
    #pragma unroll
    for (int i = 0; i < 8; ++i)
        #pragma unroll
        for (int j = 0; j < 4; ++j) acc[i][j] = z4;

    gemm256_loop(A, bm, Bt, bn, sh, acc);

    #pragma unroll
    for (int nf = 0; nf < 4; ++nf) {
        const int col = (int)bn + wc*64 + nf*16 + cl;
        const float bvv = bias[col];
        #pragma unroll
        for (int mf = 0; mf < 8; ++mf) {
            #pragma unroll
            for (int r = 0; r < 4; ++r) {
                const size_t row = bm + wr*128 + mf*16 + g*4 + r;
                out[row*D_ + col] = acc[mf][nf][r] + bvv;
            }
        }
    }
}

// ---------------------------------------------------------------------------
// Flash attention (causal), swapped-QK^T in-register softmax. (v5, verified)
// ---------------------------------------------------------------------------
__global__ __launch_bounds__(256, 4)
void attn_bf16(const u16* __restrict__ Q, const u16* __restrict__ K,
               const u16* __restrict__ Vt, u16* __restrict__ out)
{
    __shared__ u16 Ks[2][64*64];
    __shared__ u16 Vs[2][64*64];

    const int tid  = threadIdx.x;
    const int lane = tid & 63;
    const int wave = tid >> 6;
    const int cl = lane & 15;
    const int g  = lane >> 4;
    const int swz = cl & 7;
    const int pair = blockIdx.x, h = blockIdx.y, b = blockIdx.z;
    const size_t base  = ((size_t)(b*H_ + h)) * S_ * HD_;   // Q,K: [s][d]
    const size_t vbase = ((size_t)(b*H_ + h)) * HD_ * S_;   // Vt: [d][s]

    int qt = pair;
    const int n0 = pair + 1;           // tiles in part 0; total = 33

    const int r0 = tid >> 3;
    const int c0 = tid & 7;

    bf16x8 qf[2];
    #pragma unroll
    for (int ks = 0; ks < 2; ++ks)
        qf[ks] = *(const bf16x8*)&Q[base +
            (size_t)(qt*64 + wave*16 + cl)*HD_ + ks*32 + g*8];

    ush8 kreg[2], vreg[2];
    #pragma unroll
    for (int p = 0; p < 2; ++p) {
        kreg[p] = *(const ush8*)&K [base  + (size_t)(r0 + p*32)*HD_ + c0*8];
        vreg[p] = *(const ush8*)&Vt[vbase + (size_t)(r0 + p*32)*S_  + c0*8];
    }

    const f32x4 z4 = {0.f, 0.f, 0.f, 0.f};
    f32x4 oac[4];
    float m_i = -3.0e38f, l_i = 0.f;
    #pragma unroll
    for (int nf = 0; nf < 4; ++nf) oac[nf] = z4;

    int cur = 0;
    for (int t = 0; t < NT_ + 1; ++t) {
        const int kt = (t >= n0) ? t - n0 : t;

        if (t == n0) {
            const float inv = 1.f / l_i;
            const int srow = qt*64 + wave*16 + cl;
            #pragma unroll
            for (int nf = 0; nf < 4; ++nf) {
                ush4 o4;
                #pragma unroll
                for (int r = 0; r < 4; ++r) o4[r] = f2b(oac[nf][r] * inv);
                *(ush4*)&out[(size_t)(b*S_ + srow)*D_ + h*HD_ + nf*16 + g*4] = o4;
            }
            qt = NT_ - 1 - pair;
            #pragma unroll
            for (int ks = 0; ks < 2; ++ks)
                qf[ks] = *(const bf16x8*)&Q[base +
                    (size_t)(qt*64 + wave*16 + cl)*HD_ + ks*32 + g*8];
            m_i = -3.0e38f; l_i = 0.f;
            #pragma unroll
            for (int nf = 0; nf < 4; ++nf) oac[nf] = z4;
        }

        #pragma unroll
        for (int p = 0; p < 2; ++p) {
            const int row = r0 + p*32;
            const int slot = (c0 ^ (row & 7)) * 8;
            *(ush8*)&Ks[cur][row*64 + slot] = kreg[p];
            *(ush8*)&Vs[cur][row*64 + slot] = vreg[p];
        }
        __syncthreads();

        if (t + 1 < NT_ + 1) {
            const int nkt = (t + 1 >= n0) ? t + 1 - n0 : t + 1;
            #pragma unroll
            for (int p = 0; p < 2; ++p) {
                kreg[p] = *(const ush8*)&K [base  +
                    (size_t)(nkt*64 + r0 + p*32)*HD_ + c0*8];
                vreg[p] = *(const ush8*)&Vt[vbase +
                    (size_t)(r0 + p*32)*S_ + nkt*64 + c0*8];
            }
        }

        f32x4 sac[4];
        #pragma unroll
        for (int nf = 0; nf < 4; ++nf) sac[nf] = z4;
        __builtin_amdgcn_s_setprio(1);
        #pragma unroll
        for (int ks = 0; ks < 2; ++ks) {
            const int slot = ((ks*4 + g) ^ swz) * 8;
            #pragma unroll
            for (int nf = 0; nf < 4; ++nf) {
                const bf16x8 kf =
                    *(const bf16x8*)&Ks[cur][(nf*16 + cl)*64 + slot];
                sac[nf] = __builtin_amdgcn_mfma_f32_16x16x32_bf16(
                    kf, qf[ks], sac[nf], 0, 0, 0);
            }
        }
        __builtin_amdgcn_s_setprio(0);

        if (kt == qt) {
            const int qloc = wave*16 + cl;
            #pragma unroll
            for (int nf = 0; nf < 4; ++nf)
                #pragma unroll
                for (int r = 0; r < 4; ++r)
                    if (nf*16 + g*4 + r > qloc) sac[nf][r] = -3.0e38f;
        }

        float mx = -3.0e38f;
        #pragma unroll
        for (int nf = 0; nf < 4; ++nf)
            #pragma unroll
            for (int r = 0; r < 4; ++r) mx = fmaxf(mx, sac[nf][r]);
        mx = fmaxf(mx, __shfl_xor(mx, 16));
        mx = fmaxf(mx, __shfl_xor(mx, 32));
        const float mnew = fmaxf(m_i, mx);
        const float es = EXP2(m_i - mnew);
        float ls = 0.f;
        #pragma unroll
        for (int nf = 0; nf < 4; ++nf) {
            float s0 = EXP2(sac[nf][0] - mnew);
            float s1 = EXP2(sac[nf][1] - mnew);
            float s2 = EXP2(sac[nf][2] - mnew);
            float s3 = EXP2(sac[nf][3] - mnew);
            sac[nf][0] = s0; sac[nf][1] = s1; sac[nf][2] = s2; sac[nf][3] = s3;
            ls += (s0 + s1) + (s2 + s3);
        }
        ls += __shfl_xor(ls, 16);
        ls += __shfl_xor(ls, 32);
        m_i = mnew;
        l_i = l_i * es + ls;
        #pragma unroll
        for (int nf = 0; nf < 4; ++nf)
            #pragma unroll
            for (int r = 0; r < 4; ++r) oac[nf][r] *= es;

        int X[4], Y[4];
        #pragma unroll
        for (int nf = 0; nf < 4; ++nf) {
            X[nf] = cvt_pk_bf16(sac[nf][0], sac[nf][1]);
            Y[nf] = cvt_pk_bf16(sac[nf][2], sac[nf][3]);
        }

        const int sA = cl + ((g & 1) << 5);
        const bool hi = (g >> 1) != 0;
        __builtin_amdgcn_s_setprio(1);
        #pragma unroll
        for (int ks = 0; ks < 2; ++ks) {
            const int x0 = __shfl(X[2*ks],   sA);
            const int x1 = __shfl(X[2*ks+1], sA);
            const int y0 = __shfl(Y[2*ks],   sA);
            const int y1 = __shfl(Y[2*ks+1], sA);
            const int x2 = __shfl(X[2*ks],   sA + 16);
            const int x3 = __shfl(X[2*ks+1], sA + 16);
            const int y2 = __shfl(Y[2*ks],   sA + 16);
            const int y3 = __shfl(Y[2*ks+1], sA + 16);
            int4 w;
            w.x = hi ? x1 : x0;
            w.y = hi ? y1 : y0;
            w.z = hi ? x3 : x2;
            w.w = hi ? y3 : y2;
            const bf16x8 pb = __builtin_bit_cast(bf16x8, w);
            const int slot = ((ks*4 + g) ^ swz) * 8;
            #pragma unroll
            for (int nfd = 0; nfd < 4; ++nfd) {
                const bf16x8 vf =
                    *(const bf16x8*)&Vs[cur][(nfd*16 + cl)*64 + slot];
                oac[nfd] = __builtin_amdgcn_mfma_f32_16x16x32_bf16(
                    vf, pb, oac[nfd], 0, 0, 0);
            }
        }
        __builtin_amdgcn_s_setprio(0);
        cur ^= 1;
    }

    {
        const float inv = 1.f / l_i;
        const int srow = qt*64 + wave*16 + cl;
        #pragma unroll
        for (int nf = 0; nf < 4; ++nf) {
            ush4 o4;
            #pragma unroll
            for (int r = 0; r < 4; ++r) o4[r] = f2b(oac[nf][r] * inv);
            *(ush4*)&out[(size_t)(b*S_ + srow)*D_ + h*HD_ + nf*16 + g*4] = o4;
        }
    }
}

// ---------------------------------------------------------------------------
extern "C" void kernel_launch(void* const* d_in, const int* in_sizes, int n_in,
                              void* d_out, int out_size, void* d_ws, size_t ws_size,
                              hipStream_t stream)
{
    const float* x    = (const float*)d_in[0];
    const float* Wq_w = (const float*)d_in[1];
    const float* Wq_b = (const float*)d_in[2];
    const float* Wk_w = (const float*)d_in[3];
    const float* Wk_b = (const float*)d_in[4];
    const float* Wv_w = (const float*)d_in[5];
    const float* Wv_b = (const float*)d_in[6];
    const float* Wo_w = (const float*)d_in[7];
    const float* Wo_b = (const float*)d_in[8];
    float* out = (float*)d_out;

    u16* xb    = (u16*)d_ws;                       // [M_][D_] bf16
    u16* wqt   = xb  + (size_t)M_*D_;              // [N][K] bf16
    u16* wkt   = wqt + (size_t)D_*D_;
    u16* wvt   = wkt + (size_t)D_*D_;
    u16* wot   = wvt + (size_t)D_*D_;
    u16* q     = wot + (size_t)D_*D_;              // [B,H,S,HD]
    u16* k     = q   + (size_t)M_*D_;              // [B,H,S,HD]
    u16* vt    = k   + (size_t)M_*D_;              // [B,H,HD,S]
    u16* attnb = vt  + (size_t)M_*D_;              // [M_][D_]

    cast_f32_bf16<<<2048, 256, 0, stream>>>(x, xb, M_*D_/8);
    transpose_cast<<<dim3(16,16), 256, 0, stream>>>(Wq_w, wqt);
    transpose_cast<<<dim3(16,16), 256, 0, stream>>>(Wk_w, wkt);
    transpose_cast<<<dim3(16,16), 256, 0, stream>>>(Wv_w, wvt);
    transpose_cast<<<dim3(16,16), 256, 0, stream>>>(Wo_w, wot);

    gemm_qkv256<<<dim3(M_/256, 12), 512, 0, stream>>>(
        xb, wqt, wkt, wvt, Wq_b, Wk_b, Wv_b, q, k, vt);

    attn_bf16<<<dim3(NT_/2, H_, B_), 256, 0, stream>>>(q, k, vt, attnb);

    gemm_oproj256<<<dim3(M_/256, D_/256), 512, 0, stream>>>(attnb, wot, Wo_b, out);
}

// Round 9
// 272.776 us; speedup vs baseline: 1.7799x; 1.0766x over previous
//
#include <hip/hip_runtime.h>
#include <hip/hip_bf16.h>

// MHA B=4,S=2048,D=1024,H=16,HD=64 — bf16 MFMA pipeline, fp32 accum/softmax.
// v7 (resubmit, audited): attn QBLK=128 (8 waves, 512 blocks — halves KV
// traffic+staging); GEMMs 128x128/BK=64 1-barrier dbuf, exact-round grids
// (1536, 512); transpose_cast fused into one launch.

#define B_  4
#define S_  2048
#define D_  1024
#define H_  16
#define HD_ 64
#define M_  (B_*S_)   // 8192
#define NKV_ 32       // kv tiles of 64

typedef unsigned short u16;
typedef __attribute__((ext_vector_type(8))) short bf16x8;
typedef __attribute__((ext_vector_type(4))) float f32x4;
typedef __attribute__((ext_vector_type(8))) unsigned short ush8;
typedef __attribute__((ext_vector_type(4))) unsigned short ush4;

static __device__ __forceinline__ u16 f2b(float f) {
    unsigned int u = __float_as_uint(f);
    return (u16)((u + 0x7fffu + ((u >> 16) & 1u)) >> 16);
}

static __device__ __forceinline__ int cvt_pk_bf16(float a, float b) {
    int r;
    asm("v_cvt_pk_bf16_f32 %0, %1, %2" : "=v"(r) : "v"(a), "v"(b));
    return r;
}

#define EXP2(x) exp2f(x)

#define GLOAD_LDS16(g, l)                                                      \
    __builtin_amdgcn_global_load_lds(                                          \
        (const __attribute__((address_space(1))) void*)(g),                    \
        (__attribute__((address_space(3))) void*)(l), 16, 0, 0)

#define QSCALE 0.18033688f   // 0.125 * log2(e)

// ---------------------------------------------------------------------------
__global__ __launch_bounds__(256)
void cast_f32_bf16(const float* __restrict__ in, u16* __restrict__ out, int n8)
{
    int i = blockIdx.x * blockDim.x + threadIdx.x;
    const int stride = gridDim.x * blockDim.x;
    for (; i < n8; i += stride) {
        const float4 a = ((const float4*)in)[i*2+0];
        const float4 b = ((const float4*)in)[i*2+1];
        ush8 o;
        o[0]=f2b(a.x); o[1]=f2b(a.y); o[2]=f2b(a.z); o[3]=f2b(a.w);
        o[4]=f2b(b.x); o[5]=f2b(b.y); o[6]=f2b(b.z); o[7]=f2b(b.w);
        ((ush8*)out)[i] = o;
    }
}

// ---------------------------------------------------------------------------
// W [K][N] fp32 -> Wt [N][K] bf16 (64x64 tiles); z selects which W.
// ---------------------------------------------------------------------------
__global__ __launch_bounds__(256)
void transpose_cast4(const float* __restrict__ W0, const float* __restrict__ W1,
                     const float* __restrict__ W2, const float* __restrict__ W3,
                     u16* __restrict__ T0, u16* __restrict__ T1,
                     u16* __restrict__ T2, u16* __restrict__ T3)
{
    __shared__ u16 T[64*72];
    const int z = blockIdx.z;
    const float* W = z == 0 ? W0 : z == 1 ? W1 : z == 2 ? W2 : W3;
    u16* Wt = z == 0 ? T0 : z == 1 ? T1 : z == 2 ? T2 : T3;
    const int tid = threadIdx.x;
    const int k0 = blockIdx.x * 64, n0 = blockIdx.y * 64;
    #pragma unroll
    for (int it = 0; it < 4; ++it) {
        const int li = tid + it*256;
        const int kk = li >> 4;
        const int nc = (li & 15) * 4;
        const float4 w4 = *(const float4*)&W[(size_t)(k0+kk)*D_ + n0 + nc];
        T[(nc+0)*72 + kk] = f2b(w4.x);
        T[(nc+1)*72 + kk] = f2b(w4.y);
        T[(nc+2)*72 + kk] = f2b(w4.z);
        T[(nc+3)*72 + kk] = f2b(w4.w);
    }
    __syncthreads();
    #pragma unroll
    for (int it = 0; it < 2; ++it) {
        const int li = tid + it*256;
        const int nr = li >> 3;
        const int kc = (li & 7) * 8;
        const ush8 v = *(const ush8*)&T[nr*72 + kc];
        *(ush8*)&Wt[(size_t)(n0+nr)*D_ + k0 + kc] = v;
    }
}

// ---------------------------------------------------------------------------
// 128x128 GEMM core, BK=64, 4 waves (2x2), double-buffered LDS (64KB),
// one __syncthreads per K-tile. Chunk-XOR swizzle: global chunk pre-swizzled
// on the gload_lds SOURCE, ds_read applies the same XOR.
// ---------------------------------------------------------------------------
__device__ __forceinline__ void gemm128_core(
    const u16* __restrict__ Ag, size_t arow0,
    const u16* __restrict__ Bg, size_t brow0,
    u16* __restrict__ sh, f32x4 (&acc)[4][4])
{
    const int tid  = threadIdx.x;
    const int lane = tid & 63;
    const int wave = tid >> 6;
    const int wr = wave >> 1, wc = wave & 1;
    const int cl = lane & 15, g = lane >> 4;
    const int sw = cl & 7;
    const int srow   = lane >> 3;
    const int schunk = (lane & 7) ^ srow;
    u16* const Ab = sh;            // [2][128*64]
    u16* const Bb = sh + 16384;    // [2][128*64]

    auto stage = [&](int k0, u16* la, u16* lb) {
        #pragma unroll
        for (int i = 0; i < 4; ++i) {
            const int seg = wave*4 + i;   // 16 segs x 8 rows
            GLOAD_LDS16(Ag + (arow0 + seg*8 + srow)*(size_t)D_ + k0 + schunk*8,
                        la + seg*512);
            GLOAD_LDS16(Bg + (brow0 + seg*8 + srow)*(size_t)D_ + k0 + schunk*8,
                        lb + seg*512);
        }
    };

    stage(0, Ab, Bb);
    __syncthreads();

    for (int t = 0; t < 16; ++t) {
        u16* const Ac = Ab + (t & 1) * 8192;
        u16* const Bc = Bb + (t & 1) * 8192;

        bf16x8 af[4][2], bf[4][2];
        #pragma unroll
        for (int mf = 0; mf < 4; ++mf)
            #pragma unroll
            for (int ks = 0; ks < 2; ++ks)
                af[mf][ks] = *(const bf16x8*)
                    &Ac[(wr*64 + mf*16 + cl)*64 + (((ks*4 + g) ^ sw) * 8)];
        #pragma unroll
        for (int nf = 0; nf < 4; ++nf)
            #pragma unroll
            for (int ks = 0; ks < 2; ++ks)
                bf[nf][ks] = *(const bf16x8*)
                    &Bc[(wc*64 + nf*16 + cl)*64 + (((ks*4 + g) ^ sw) * 8)];

        if (t < 15)
            stage((t + 1) * 64, Ab + ((t + 1) & 1) * 8192,
                                Bb + ((t + 1) & 1) * 8192);

        __builtin_amdgcn_s_setprio(1);
        #pragma unroll
        for (int ks = 0; ks < 2; ++ks)
            #pragma unroll
            for (int mf = 0; mf < 4; ++mf)
                #pragma unroll
                for (int nf = 0; nf < 4; ++nf)
                    acc[mf][nf] = __builtin_amdgcn_mfma_f32_16x16x32_bf16(
                        af[mf][ks], bf[nf][ks], acc[mf][nf], 0, 0, 0);
        __builtin_amdgcn_s_setprio(0);
        __syncthreads();   // drains vmcnt (hipcc) -> next tile staged+visible
    }
}

// ---------------------------------------------------------------------------
// Fused QKV GEMM 128x128. by: sel = by>>3 (0=Q,1=K,2=V), bn = (by&7)*128.
// Q/K -> bf16 [b,h,s,d] (Q scaled); V -> [b,h,d,s] via LDS re-transpose.
// Grid 64 x 24 = 1536 = 3 exact rounds at 2 blocks/CU.
// ---------------------------------------------------------------------------
__global__ __launch_bounds__(256, 2)
void gemm_qkv128(const u16* __restrict__ A,
                 const u16* __restrict__ wq, const u16* __restrict__ wk,
                 const u16* __restrict__ wv,
                 const float* __restrict__ bq, const float* __restrict__ bk,
                 const float* __restrict__ bv,
                 u16* __restrict__ oq, u16* __restrict__ ok,
                 u16* __restrict__ ovt)
{
    __shared__ u16 sh[32768];   // 64KB: GEMM dbuf; reused as T[128][136] for V
    const int tid  = threadIdx.x;
    const int lane = tid & 63;
    const int wave = tid >> 6;
    const int wr = wave >> 1, wc = wave & 1;
    const int cl = lane & 15, g = lane >> 4;
    const size_t bm = (size_t)blockIdx.x * 128;
    const int by  = blockIdx.y;
    const int sel = by >> 3;
    const int bn  = (by & 7) * 128;
    const u16* Bt = sel == 0 ? wq : sel == 1 ? wk : wv;
    const float* bias = sel == 0 ? bq : sel == 1 ? bk : bv;

    f32x4 acc[4][4];
    const f32x4 z4 = {0.f, 0.f, 0.f, 0.f};
    #pragma unroll
    for (int i = 0; i < 4; ++i)
        #pragma unroll
        for (int j = 0; j < 4; ++j) acc[i][j] = z4;

    gemm128_core(A, bm, Bt, (size_t)bn, sh, acc);

    if (sel == 2) {
        // V: transpose via LDS (pitch 136 u16 = 16B-aligned rows).
        const int b  = (int)(bm >> 11);
        const int s0 = (int)(bm & (S_ - 1));
        #pragma unroll
        for (int nf = 0; nf < 4; ++nf) {
            const int col = wc*64 + nf*16 + cl;     // 0..127 within bn-block
            const float bvv = bias[bn + col];
            #pragma unroll
            for (int mf = 0; mf < 4; ++mf) {
                ush4 o4;
                #pragma unroll
                for (int r = 0; r < 4; ++r) o4[r] = f2b(acc[mf][nf][r] + bvv);
                *(ush4*)&sh[col*136 + wr*64 + mf*16 + g*4] = o4;
            }
        }
        __syncthreads();
        #pragma unroll
        for (int it = 0; it < 8; ++it) {
            const int lin = it*256 + tid;           // 0..2047
            const int d2 = lin >> 4, sc = lin & 15; // d2: 0..127, sc: 0..15
            const int hh = (bn >> 6) + (d2 >> 6);
            const int d  = d2 & 63;
            const ush8 vv = *(const ush8*)&sh[d2*136 + sc*8];
            *(ush8*)&ovt[((size_t)((b*H_ + hh)*HD_ + d))*S_ + s0 + sc*8] = vv;
        }
    } else {
        const float osc = sel == 0 ? QSCALE : 1.0f;
        u16* o = sel == 0 ? oq : ok;
        #pragma unroll
        for (int nf = 0; nf < 4; ++nf) {
            const int col = bn + wc*64 + nf*16 + cl;
            const float bvv = bias[col];
            const int h = col >> 6, d = col & (HD_ - 1);
            #pragma unroll
            for (int mf = 0; mf < 4; ++mf) {
                #pragma unroll
                for (int r = 0; r < 4; ++r) {
                    const size_t row = bm + wr*64 + mf*16 + g*4 + r;
                    const int bb = (int)(row >> 11), s = (int)(row & (S_ - 1));
                    o[((size_t)(bb*H_ + h)*S_ + s)*HD_ + d] =
                        f2b((acc[mf][nf][r] + bvv) * osc);
                }
            }
        }
    }
}

// ---------------------------------------------------------------------------
// O-proj GEMM 128x128, fp32 out. Grid 64 x 8 = 512 = 1 exact round.
// ---------------------------------------------------------------------------
__global__ __launch_bounds__(256, 2)
void gemm_oproj128(const u16* __restrict__ A, const u16* __restrict__ Bt,
                   const float* __restrict__ bias, float* __restrict__ out)
{
    __shared__ u16 sh[32768];
    const int tid  = threadIdx.x;
    const int lane = tid & 63;
    const int wave = tid >> 6;
    const int wr = wave >> 1, wc = wave & 1;
    const int cl = lane & 15, g = lane >> 4;
    const size_t bm = (size_t)blockIdx.x * 128;
    const size_t bn = (size_t)blockIdx.y * 128;

    f32x4 acc[4][4];
    const f32x4 z4 = {0.f, 0.f, 0.f, 0.f};
    #pragma unroll
    for (int i = 0; i < 4; ++i)
        #pragma unroll
        for (int j = 0; j < 4; ++j) acc[i][j] = z4;

    gemm128_core(A, bm, Bt, bn, sh, acc);

    #pragma unroll
    for (int nf = 0; nf < 4; ++nf) {
        const int col = (int)bn + wc*64 + nf*16 + cl;
        const float bvv = bias[col];
        #pragma unroll
        for (int mf = 0; mf < 4; ++mf) {
            #pragma unroll
            for (int r = 0; r < 4; ++r) {
                const size_t row = bm + wr*64 + mf*16 + g*4 + r;
                out[row*D_ + col] = acc[mf][nf][r] + bvv;
            }
        }
    }
}

// ---------------------------------------------------------------------------
// Flash attention (causal), swapped-QK^T in-register softmax, QBLK=128:
// 8 waves x 16 q-rows. Triangle pairing over 16 q-tiles of 128 rows:
// block does qt2 = pair and 15-pair (34 kv-tile units, uniform).
// K: [b,h,s,d]; V pre-transposed [b,h,d,s]. LDS dbuf, 1 barrier/tile.
// Per-thread staging: 1 K + 1 V ush8 load per tile (512 threads cover 64x64).
// ---------------------------------------------------------------------------
__global__ __launch_bounds__(512, 2)
void attn_bf16(const u16* __restrict__ Q, const u16* __restrict__ K,
               const u16* __restrict__ Vt, u16* __restrict__ out)
{
    __shared__ u16 Ks[2][64*64];
    __shared__ u16 Vs[2][64*64];

    const int tid  = threadIdx.x;
    const int lane = tid & 63;
    const int wave = tid >> 6;         // 0..7
    const int cl = lane & 15;
    const int g  = lane >> 4;
    const int swz = cl & 7;
    const int pair = blockIdx.x, h = blockIdx.y, b = blockIdx.z;
    const size_t base  = ((size_t)(b*H_ + h)) * S_ * HD_;   // Q,K: [s][d]
    const size_t vbase = ((size_t)(b*H_ + h)) * HD_ * S_;   // Vt: [d][s]

    int qt2 = pair;                    // q-tile of 128 rows
    const int n0 = 2*pair + 2;         // kv tiles in part 0; total = 34

    const int r0 = tid >> 3;           // 0..63
    const int c0 = tid & 7;

    bf16x8 qf[2];
    #pragma unroll
    for (int ks = 0; ks < 2; ++ks)
        qf[ks] = *(const bf16x8*)&Q[base +
            (size_t)(qt2*128 + wave*16 + cl)*HD_ + ks*32 + g*8];

    ush8 kreg, vreg;
    kreg = *(const ush8*)&K [base  + (size_t)r0*HD_ + c0*8];
    vreg = *(const ush8*)&Vt[vbase + (size_t)r0*S_  + c0*8];

    const f32x4 z4 = {0.f, 0.f, 0.f, 0.f};
    f32x4 oac[4];
    float m_i = -3.0e38f, l_i = 0.f;
    #pragma unroll
    for (int nf = 0; nf < 4; ++nf) oac[nf] = z4;

    int cur = 0;
    for (int t = 0; t < 34; ++t) {
        const int kt = (t >= n0) ? t - n0 : t;

        if (t == n0) {
            const float inv = 1.f / l_i;
            const int srow = qt2*128 + wave*16 + cl;
            #pragma unroll
            for (int nf = 0; nf < 4; ++nf) {
                ush4 o4;
                #pragma unroll
                for (int r = 0; r < 4; ++r) o4[r] = f2b(oac[nf][r] * inv);
                *(ush4*)&out[(size_t)(b*S_ + srow)*D_ + h*HD_ + nf*16 + g*4] = o4;
            }
            qt2 = 15 - pair;
            #pragma unroll
            for (int ks = 0; ks < 2; ++ks)
                qf[ks] = *(const bf16x8*)&Q[base +
                    (size_t)(qt2*128 + wave*16 + cl)*HD_ + ks*32 + g*8];
            m_i = -3.0e38f; l_i = 0.f;
            #pragma unroll
            for (int nf = 0; nf < 4; ++nf) oac[nf] = z4;
        }

        // commit prefetched tile (chunk-XOR swizzle)
        {
            const int slot = (c0 ^ (r0 & 7)) * 8;
            *(ush8*)&Ks[cur][r0*64 + slot] = kreg;
            *(ush8*)&Vs[cur][r0*64 + slot] = vreg;
        }
        __syncthreads();

        if (t + 1 < 34) {
            const int nkt = (t + 1 >= n0) ? t + 1 - n0 : t + 1;
            kreg = *(const ush8*)&K [base  + (size_t)(nkt*64 + r0)*HD_ + c0*8];
            vreg = *(const ush8*)&Vt[vbase + (size_t)r0*S_ + nkt*64 + c0*8];
        }

        // S^T = K·Q^T : sac[nf][r] = S[kv_local = nf*16+g*4+r][q = cl]
        f32x4 sac[4];
        #pragma unroll
        for (int nf = 0; nf < 4; ++nf) sac[nf] = z4;
        __builtin_amdgcn_s_setprio(1);
        #pragma unroll
        for (int ks = 0; ks < 2; ++ks) {
            const int slot = ((ks*4 + g) ^ swz) * 8;
            #pragma unroll
            for (int nf = 0; nf < 4; ++nf) {
                const bf16x8 kf =
                    *(const bf16x8*)&Ks[cur][(nf*16 + cl)*64 + slot];
                sac[nf] = __builtin_amdgcn_mfma_f32_16x16x32_bf16(
                    kf, qf[ks], sac[nf], 0, 0, 0);
            }
        }
        __builtin_amdgcn_s_setprio(0);

        // causal mask: kv_global > q_global <=> dkt*64 + kvl > qloc
        const int dkt = kt - 2*qt2;
        if (dkt >= 0) {
            const int qloc = wave*16 + cl;
            #pragma unroll
            for (int nf = 0; nf < 4; ++nf)
                #pragma unroll
                for (int r = 0; r < 4; ++r)
                    if (dkt*64 + nf*16 + g*4 + r > qloc) sac[nf][r] = -3.0e38f;
        }

        float mx = -3.0e38f;
        #pragma unroll
        for (int nf = 0; nf < 4; ++nf)
            #pragma unroll
            for (int r = 0; r < 4; ++r) mx = fmaxf(mx, sac[nf][r]);
        mx = fmaxf(mx, __shfl_xor(mx, 16));
        mx = fmaxf(mx, __shfl_xor(mx, 32));
        const float mnew = fmaxf(m_i, mx);
        const float es = EXP2(m_i - mnew);
        float ls = 0.f;
        #pragma unroll
        for (int nf = 0; nf < 4; ++nf) {
            float s0 = EXP2(sac[nf][0] - mnew);
            float s1 = EXP2(sac[nf][1] - mnew);
            float s2 = EXP2(sac[nf][2] - mnew);
            float s3 = EXP2(sac[nf][3] - mnew);
            sac[nf][0] = s0; sac[nf][1] = s1; sac[nf][2] = s2; sac[nf][3] = s3;
            ls += (s0 + s1) + (s2 + s3);
        }
        ls += __shfl_xor(ls, 16);
        ls += __shfl_xor(ls, 32);
        m_i = mnew;
        l_i = l_i * es + ls;
        #pragma unroll
        for (int nf = 0; nf < 4; ++nf)
            #pragma unroll
            for (int r = 0; r < 4; ++r) oac[nf][r] *= es;

        int X[4], Y[4];
        #pragma unroll
        for (int nf = 0; nf < 4; ++nf) {
            X[nf] = cvt_pk_bf16(sac[nf][0], sac[nf][1]);
            Y[nf] = cvt_pk_bf16(sac[nf][2], sac[nf][3]);
        }

        const int sA = cl + ((g & 1) << 5);
        const bool hi = (g >> 1) != 0;
        __builtin_amdgcn_s_setprio(1);
        #pragma unroll
        for (int ks = 0; ks < 2; ++ks) {
            const int x0 = __shfl(X[2*ks],   sA);
            const int x1 = __shfl(X[2*ks+1], sA);
            const int y0 = __shfl(Y[2*ks],   sA);
            const int y1 = __shfl(Y[2*ks+1], sA);
            const int x2 = __shfl(X[2*ks],   sA + 16);
            const int x3 = __shfl(X[2*ks+1], sA + 16);
            const int y2 = __shfl(Y[2*ks],   sA + 16);
            const int y3 = __shfl(Y[2*ks+1], sA + 16);
            int4 w;
            w.x = hi ? x1 : x0;
            w.y = hi ? y1 : y0;
            w.z = hi ? x3 : x2;
            w.w = hi ? y3 : y2;
            const bf16x8 pb = __builtin_bit_cast(bf16x8, w);
            const int slot = ((ks*4 + g) ^ swz) * 8;
            #pragma unroll
            for (int nfd = 0; nfd < 4; ++nfd) {
                const bf16x8 vf =
                    *(const bf16x8*)&Vs[cur][(nfd*16 + cl)*64 + slot];
                oac[nfd] = __builtin_amdgcn_mfma_f32_16x16x32_bf16(
                    vf, pb, oac[nfd], 0, 0, 0);
            }
        }
        __builtin_amdgcn_s_setprio(0);
        cur ^= 1;
    }

    {
        const float inv = 1.f / l_i;
        const int srow = qt2*128 + wave*16 + cl;
        #pragma unroll
        for (int nf = 0; nf < 4; ++nf) {
            ush4 o4;
            #pragma unroll
            for (int r = 0; r < 4; ++r) o4[r] = f2b(oac[nf][r] * inv);
            *(ush4*)&out[(size_t)(b*S_ + srow)*D_ + h*HD_ + nf*16 + g*4] = o4;
        }
    }
}

// ---------------------------------------------------------------------------
extern "C" void kernel_launch(void* const* d_in, const int* in_sizes, int n_in,
                              void* d_out, int out_size, void* d_ws, size_t ws_size,
                              hipStream_t stream)
{
    const float* x    = (const float*)d_in[0];
    const float* Wq_w = (const float*)d_in[1];
    const float* Wq_b = (const float*)d_in[2];
    const float* Wk_w = (const float*)d_in[3];
    const float* Wk_b = (const float*)d_in[4];
    const float* Wv_w = (const float*)d_in[5];
    const float* Wv_b = (const float*)d_in[6];
    const float* Wo_w = (const float*)d_in[7];
    const float* Wo_b = (const float*)d_in[8];
    float* out = (float*)d_out;

    u16* xb    = (u16*)d_ws;                       // [M_][D_] bf16
    u16* wqt   = xb  + (size_t)M_*D_;              // [N][K] bf16
    u16* wkt   = wqt + (size_t)D_*D_;
    u16* wvt   = wkt + (size_t)D_*D_;
    u16* wot   = wvt + (size_t)D_*D_;
    u16* q     = wot + (size_t)D_*D_;              // [B,H,S,HD]
    u16* k     = q   + (size_t)M_*D_;              // [B,H,S,HD]
    u16* vt    = k   + (size_t)M_*D_;              // [B,H,HD,S]
    u16* attnb = vt  + (size_t)M_*D_;              // [M_][D_]

    cast_f32_bf16<<<2048, 256, 0, stream>>>(x, xb, M_*D_/8);
    transpose_cast4<<<dim3(16,16,4), 256, 0, stream>>>(
        Wq_w, Wk_w, Wv_w, Wo_w, wqt, wkt, wvt, wot);

    gemm_qkv128<<<dim3(M_/128, 24), 256, 0, stream>>>(
        xb, wqt, wkt, wvt, Wq_b, Wk_b, Wv_b, q, k, vt);

    attn_bf16<<<dim3(8, H_, B_), 512, 0, stream>>>(q, k, vt, attnb);

    gemm_oproj128<<<dim3(M_/128, D_/128), 256, 0, stream>>>(attnb, wot, Wo_b, out);
}

// Round 10
// 257.383 us; speedup vs baseline: 1.8864x; 1.0598x over previous
//
#include <hip/hip_runtime.h>
#include <hip/hip_bf16.h>

// MHA B=4,S=2048,D=1024,H=16,HD=64 — bf16 MFMA pipeline, fp32 accum/softmax.
// v8 = v7 + (1) GEMM core counted-vmcnt pipeline: raw s_barrier + vmcnt(8)
// keeps next-tile global_load_lds in flight across barriers (T3/T4 essence);
// (2) attn defer-max (T13): skip O-rescale when __all(mx - m_i <= 8).

#define B_  4
#define S_  2048
#define D_  1024
#define H_  16
#define HD_ 64
#define M_  (B_*S_)   // 8192
#define NKV_ 32       // kv tiles of 64

typedef unsigned short u16;
typedef __attribute__((ext_vector_type(8))) short bf16x8;
typedef __attribute__((ext_vector_type(4))) float f32x4;
typedef __attribute__((ext_vector_type(8))) unsigned short ush8;
typedef __attribute__((ext_vector_type(4))) unsigned short ush4;

static __device__ __forceinline__ u16 f2b(float f) {
    unsigned int u = __float_as_uint(f);
    return (u16)((u + 0x7fffu + ((u >> 16) & 1u)) >> 16);
}

static __device__ __forceinline__ int cvt_pk_bf16(float a, float b) {
    int r;
    asm("v_cvt_pk_bf16_f32 %0, %1, %2" : "=v"(r) : "v"(a), "v"(b));
    return r;
}

#define EXP2(x) exp2f(x)

#define GLOAD_LDS16(g, l)                                                      \
    __builtin_amdgcn_global_load_lds(                                          \
        (const __attribute__((address_space(1))) void*)(g),                    \
        (__attribute__((address_space(3))) void*)(l), 16, 0, 0)

#define QSCALE 0.18033688f   // 0.125 * log2(e)

// ---------------------------------------------------------------------------
__global__ __launch_bounds__(256)
void cast_f32_bf16(const float* __restrict__ in, u16* __restrict__ out, int n8)
{
    int i = blockIdx.x * blockDim.x + threadIdx.x;
    const int stride = gridDim.x * blockDim.x;
    for (; i < n8; i += stride) {
        const float4 a = ((const float4*)in)[i*2+0];
        const float4 b = ((const float4*)in)[i*2+1];
        ush8 o;
        o[0]=f2b(a.x); o[1]=f2b(a.y); o[2]=f2b(a.z); o[3]=f2b(a.w);
        o[4]=f2b(b.x); o[5]=f2b(b.y); o[6]=f2b(b.z); o[7]=f2b(b.w);
        ((ush8*)out)[i] = o;
    }
}

// ---------------------------------------------------------------------------
// W [K][N] fp32 -> Wt [N][K] bf16 (64x64 tiles); z selects which W.
// ---------------------------------------------------------------------------
__global__ __launch_bounds__(256)
void transpose_cast4(const float* __restrict__ W0, const float* __restrict__ W1,
                     const float* __restrict__ W2, const float* __restrict__ W3,
                     u16* __restrict__ T0, u16* __restrict__ T1,
                     u16* __restrict__ T2, u16* __restrict__ T3)
{
    __shared__ u16 T[64*72];
    const int z = blockIdx.z;
    const float* W = z == 0 ? W0 : z == 1 ? W1 : z == 2 ? W2 : W3;
    u16* Wt = z == 0 ? T0 : z == 1 ? T1 : z == 2 ? T2 : T3;
    const int tid = threadIdx.x;
    const int k0 = blockIdx.x * 64, n0 = blockIdx.y * 64;
    #pragma unroll
    for (int it = 0; it < 4; ++it) {
        const int li = tid + it*256;
        const int kk = li >> 4;
        const int nc = (li & 15) * 4;
        const float4 w4 = *(const float4*)&W[(size_t)(k0+kk)*D_ + n0 + nc];
        T[(nc+0)*72 + kk] = f2b(w4.x);
        T[(nc+1)*72 + kk] = f2b(w4.y);
        T[(nc+2)*72 + kk] = f2b(w4.z);
        T[(nc+3)*72 + kk] = f2b(w4.w);
    }
    __syncthreads();
    #pragma unroll
    for (int it = 0; it < 2; ++it) {
        const int li = tid + it*256;
        const int nr = li >> 3;
        const int kc = (li & 7) * 8;
        const ush8 v = *(const ush8*)&T[nr*72 + kc];
        *(ush8*)&Wt[(size_t)(n0+nr)*D_ + k0 + kc] = v;
    }
}

// ---------------------------------------------------------------------------
// 128x128 GEMM core, BK=64, 4 waves (2x2), double-buffered LDS (64KB).
// Counted-vmcnt pipeline: per K-tile {stage next tile (8 gload_lds) ->
// s_waitcnt vmcnt(8) (drains PREVIOUS batch only; new 8 stay in flight) ->
// raw s_barrier -> ds_read frags -> MFMA -> raw s_barrier}. Last iter
// drains vmcnt(0). Chunk-XOR swizzle: source pre-swizzled, ds_read XORed.
// ---------------------------------------------------------------------------
__device__ __forceinline__ void gemm128_core(
    const u16* __restrict__ Ag, size_t arow0,
    const u16* __restrict__ Bg, size_t brow0,
    u16* __restrict__ sh, f32x4 (&acc)[4][4])
{
    const int tid  = threadIdx.x;
    const int lane = tid & 63;
    const int wave = tid >> 6;
    const int wr = wave >> 1, wc = wave & 1;
    const int cl = lane & 15, g = lane >> 4;
    const int sw = cl & 7;
    const int srow   = lane >> 3;
    const int schunk = (lane & 7) ^ srow;
    u16* const Ab = sh;            // [2][128*64]
    u16* const Bb = sh + 16384;    // [2][128*64]

    auto stage = [&](int k0, u16* la, u16* lb) {
        #pragma unroll
        for (int i = 0; i < 4; ++i) {
            const int seg = wave*4 + i;   // 16 segs x 8 rows
            GLOAD_LDS16(Ag + (arow0 + seg*8 + srow)*(size_t)D_ + k0 + schunk*8,
                        la + seg*512);
            GLOAD_LDS16(Bg + (brow0 + seg*8 + srow)*(size_t)D_ + k0 + schunk*8,
                        lb + seg*512);
        }
    };

    stage(0, Ab, Bb);                 // 8 loads outstanding (tile 0)

    for (int t = 0; t < 16; ++t) {
        u16* const Ac = Ab + (t & 1) * 8192;
        u16* const Bc = Bb + (t & 1) * 8192;

        if (t < 15) {
            // issue tile t+1 (8 more loads; up to 16 outstanding), then wait
            // until only those 8 remain -> tile t's batch has landed.
            stage((t + 1) * 64, Ab + ((t + 1) & 1) * 8192,
                                Bb + ((t + 1) & 1) * 8192);
            asm volatile("s_waitcnt vmcnt(8)" ::: "memory");
        } else {
            asm volatile("s_waitcnt vmcnt(0)" ::: "memory");
        }
        __builtin_amdgcn_sched_barrier(0);
        __builtin_amdgcn_s_barrier();       // raw: no auto vmcnt(0) drain
        __builtin_amdgcn_sched_barrier(0);

        bf16x8 af[4][2], bf[4][2];
        #pragma unroll
        for (int mf = 0; mf < 4; ++mf)
            #pragma unroll
            for (int ks = 0; ks < 2; ++ks)
                af[mf][ks] = *(const bf16x8*)
                    &Ac[(wr*64 + mf*16 + cl)*64 + (((ks*4 + g) ^ sw) * 8)];
        #pragma unroll
        for (int nf = 0; nf < 4; ++nf)
            #pragma unroll
            for (int ks = 0; ks < 2; ++ks)
                bf[nf][ks] = *(const bf16x8*)
                    &Bc[(wc*64 + nf*16 + cl)*64 + (((ks*4 + g) ^ sw) * 8)];

        __builtin_amdgcn_s_setprio(1);
        #pragma unroll
        for (int ks = 0; ks < 2; ++ks)
            #pragma unroll
            for (int mf = 0; mf < 4; ++mf)
                #pragma unroll
                for (int nf = 0; nf < 4; ++nf)
                    acc[mf][nf] = __builtin_amdgcn_mfma_f32_16x16x32_bf16(
                        af[mf][ks], bf[nf][ks], acc[mf][nf], 0, 0, 0);
        __builtin_amdgcn_s_setprio(0);

        // 2nd barrier: all reads of buf[t&1] done before anyone stages into
        // it at iter t+1 (lgkmcnt before MFMA consumption guarantees reads
        // completed before this wave arrives).
        __builtin_amdgcn_sched_barrier(0);
        __builtin_amdgcn_s_barrier();
        __builtin_amdgcn_sched_barrier(0);
    }
    __syncthreads();   // full fence before LDS reuse in epilogues
}

// ---------------------------------------------------------------------------
// Fused QKV GEMM 128x128. by: sel = by>>3 (0=Q,1=K,2=V), bn = (by&7)*128.
// Q/K -> bf16 [b,h,s,d] (Q scaled); V -> [b,h,d,s] via LDS re-transpose.
// Grid 64 x 24 = 1536 = 3 exact rounds at 2 blocks/CU.
// ---------------------------------------------------------------------------
__global__ __launch_bounds__(256, 2)
void gemm_qkv128(const u16* __restrict__ A,
                 const u16* __restrict__ wq, const u16* __restrict__ wk,
                 const u16* __restrict__ wv,
                 const float* __restrict__ bq, const float* __restrict__ bk,
                 const float* __restrict__ bv,
                 u16* __restrict__ oq, u16* __restrict__ ok,
                 u16* __restrict__ ovt)
{
    __shared__ u16 sh[32768];   // 64KB: GEMM dbuf; reused as T[128][136] for V
    const int tid  = threadIdx.x;
    const int lane = tid & 63;
    const int wave = tid >> 6;
    const int wr = wave >> 1, wc = wave & 1;
    const int cl = lane & 15, g = lane >> 4;
    const size_t bm = (size_t)blockIdx.x * 128;
    const int by  = blockIdx.y;
    const int sel = by >> 3;
    const int bn  = (by & 7) * 128;
    const u16* Bt = sel == 0 ? wq : sel == 1 ? wk : wv;
    const float* bias = sel == 0 ? bq : sel == 1 ? bk : bv;

    f32x4 acc[4][4];
    const f32x4 z4 = {0.f, 0.f, 0.f, 0.f};
    #pragma unroll
    for (int i = 0; i < 4; ++i)
        #pragma unroll
        for (int j = 0; j < 4; ++j) acc[i][j] = z4;

    gemm128_core(A, bm, Bt, (size_t)bn, sh, acc);

    if (sel == 2) {
        // V: transpose via LDS (pitch 136 u16 = 16B-aligned rows).
        const int b  = (int)(bm >> 11);
        const int s0 = (int)(bm & (S_ - 1));
        #pragma unroll
        for (int nf = 0; nf < 4; ++nf) {
            const int col = wc*64 + nf*16 + cl;     // 0..127 within bn-block
            const float bvv = bias[bn + col];
            #pragma unroll
            for (int mf = 0; mf < 4; ++mf) {
                ush4 o4;
                #pragma unroll
                for (int r = 0; r < 4; ++r) o4[r] = f2b(acc[mf][nf][r] + bvv);
                *(ush4*)&sh[col*136 + wr*64 + mf*16 + g*4] = o4;
            }
        }
        __syncthreads();
        #pragma unroll
        for (int it = 0; it < 8; ++it) {
            const int lin = it*256 + tid;           // 0..2047
            const int d2 = lin >> 4, sc = lin & 15; // d2: 0..127, sc: 0..15
            const int hh = (bn >> 6) + (d2 >> 6);
            const int d  = d2 & 63;
            const ush8 vv = *(const ush8*)&sh[d2*136 + sc*8];
            *(ush8*)&ovt[((size_t)((b*H_ + hh)*HD_ + d))*S_ + s0 + sc*8] = vv;
        }
    } else {
        const float osc = sel == 0 ? QSCALE : 1.0f;
        u16* o = sel == 0 ? oq : ok;
        #pragma unroll
        for (int nf = 0; nf < 4; ++nf) {
            const int col = bn + wc*64 + nf*16 + cl;
            const float bvv = bias[col];
            const int h = col >> 6, d = col & (HD_ - 1);
            #pragma unroll
            for (int mf = 0; mf < 4; ++mf) {
                #pragma unroll
                for (int r = 0; r < 4; ++r) {
                    const size_t row = bm + wr*64 + mf*16 + g*4 + r;
                    const int bb = (int)(row >> 11), s = (int)(row & (S_ - 1));
                    o[((size_t)(bb*H_ + h)*S_ + s)*HD_ + d] =
                        f2b((acc[mf][nf][r] + bvv) * osc);
                }
            }
        }
    }
}

// ---------------------------------------------------------------------------
// O-proj GEMM 128x128, fp32 out. Grid 64 x 8 = 512 = 1 exact round.
// ---------------------------------------------------------------------------
__global__ __launch_bounds__(256, 2)
void gemm_oproj128(const u16* __restrict__ A, const u16* __restrict__ Bt,
                   const float* __restrict__ bias, float* __restrict__ out)
{
    __shared__ u16 sh[32768];
    const int tid  = threadIdx.x;
    const int lane = tid & 63;
    const int wave = tid >> 6;
    const int wr = wave >> 1, wc = wave & 1;
    const int cl = lane & 15, g = lane >> 4;
    const size_t bm = (size_t)blockIdx.x * 128;
    const size_t bn = (size_t)blockIdx.y * 128;

    f32x4 acc[4][4];
    const f32x4 z4 = {0.f, 0.f, 0.f, 0.f};
    #pragma unroll
    for (int i = 0; i < 4; ++i)
        #pragma unroll
        for (int j = 0; j < 4; ++j) acc[i][j] = z4;

    gemm128_core(A, bm, Bt, bn, sh, acc);

    #pragma unroll
    for (int nf = 0; nf < 4; ++nf) {
        const int col = (int)bn + wc*64 + nf*16 + cl;
        const float bvv = bias[col];
        #pragma unroll
        for (int mf = 0; mf < 4; ++mf) {
            #pragma unroll
            for (int r = 0; r < 4; ++r) {
                const size_t row = bm + wr*64 + mf*16 + g*4 + r;
                out[row*D_ + col] = acc[mf][nf][r] + bvv;
            }
        }
    }
}

// ---------------------------------------------------------------------------
// Flash attention (causal), swapped-QK^T in-register softmax, QBLK=128,
// 8 waves x 16 q-rows, triangle pairing (34 kv-tile units uniform).
// v8: defer-max (T13) — skip O-rescale when __all(mx - m_i <= 8) (exp2
// domain, P bounded by 2^8, fp32 accum).
// ---------------------------------------------------------------------------
__global__ __launch_bounds__(512, 2)
void attn_bf16(const u16* __restrict__ Q, const u16* __restrict__ K,
               const u16* __restrict__ Vt, u16* __restrict__ out)
{
    __shared__ u16 Ks[2][64*64];
    __shared__ u16 Vs[2][64*64];

    const int tid  = threadIdx.x;
    const int lane = tid & 63;
    const int wave = tid >> 6;         // 0..7
    const int cl = lane & 15;
    const int g  = lane >> 4;
    const int swz = cl & 7;
    const int pair = blockIdx.x, h = blockIdx.y, b = blockIdx.z;
    const size_t base  = ((size_t)(b*H_ + h)) * S_ * HD_;   // Q,K: [s][d]
    const size_t vbase = ((size_t)(b*H_ + h)) * HD_ * S_;   // Vt: [d][s]

    int qt2 = pair;                    // q-tile of 128 rows
    const int n0 = 2*pair + 2;         // kv tiles in part 0; total = 34

    const int r0 = tid >> 3;           // 0..63
    const int c0 = tid & 7;

    bf16x8 qf[2];
    #pragma unroll
    for (int ks = 0; ks < 2; ++ks)
        qf[ks] = *(const bf16x8*)&Q[base +
            (size_t)(qt2*128 + wave*16 + cl)*HD_ + ks*32 + g*8];

    ush8 kreg, vreg;
    kreg = *(const ush8*)&K [base  + (size_t)r0*HD_ + c0*8];
    vreg = *(const ush8*)&Vt[vbase + (size_t)r0*S_  + c0*8];

    const f32x4 z4 = {0.f, 0.f, 0.f, 0.f};
    f32x4 oac[4];
    float m_i = -3.0e38f, l_i = 0.f;
    #pragma unroll
    for (int nf = 0; nf < 4; ++nf) oac[nf] = z4;

    int cur = 0;
    for (int t = 0; t < 34; ++t) {
        const int kt = (t >= n0) ? t - n0 : t;

        if (t == n0) {
            const float inv = 1.f / l_i;
            const int srow = qt2*128 + wave*16 + cl;
            #pragma unroll
            for (int nf = 0; nf < 4; ++nf) {
                ush4 o4;
                #pragma unroll
                for (int r = 0; r < 4; ++r) o4[r] = f2b(oac[nf][r] * inv);
                *(ush4*)&out[(size_t)(b*S_ + srow)*D_ + h*HD_ + nf*16 + g*4] = o4;
            }
            qt2 = 15 - pair;
            #pragma unroll
            for (int ks = 0; ks < 2; ++ks)
                qf[ks] = *(const bf16x8*)&Q[base +
                    (size_t)(qt2*128 + wave*16 + cl)*HD_ + ks*32 + g*8];
            m_i = -3.0e38f; l_i = 0.f;
            #pragma unroll
            for (int nf = 0; nf < 4; ++nf) oac[nf] = z4;
        }

        // commit prefetched tile (chunk-XOR swizzle)
        {
            const int slot = (c0 ^ (r0 & 7)) * 8;
            *(ush8*)&Ks[cur][r0*64 + slot] = kreg;
            *(ush8*)&Vs[cur][r0*64 + slot] = vreg;
        }
        __syncthreads();

        if (t + 1 < 34) {
            const int nkt = (t + 1 >= n0) ? t + 1 - n0 : t + 1;
            kreg = *(const ush8*)&K [base  + (size_t)(nkt*64 + r0)*HD_ + c0*8];
            vreg = *(const ush8*)&Vt[vbase + (size_t)r0*S_ + nkt*64 + c0*8];
        }

        // S^T = K·Q^T : sac[nf][r] = S[kv_local = nf*16+g*4+r][q = cl]
        f32x4 sac[4];
        #pragma unroll
        for (int nf = 0; nf < 4; ++nf) sac[nf] = z4;
        __builtin_amdgcn_s_setprio(1);
        #pragma unroll
        for (int ks = 0; ks < 2; ++ks) {
            const int slot = ((ks*4 + g) ^ swz) * 8;
            #pragma unroll
            for (int nf = 0; nf < 4; ++nf) {
                const bf16x8 kf =
                    *(const bf16x8*)&Ks[cur][(nf*16 + cl)*64 + slot];
                sac[nf] = __builtin_amdgcn_mfma_f32_16x16x32_bf16(
                    kf, qf[ks], sac[nf], 0, 0, 0);
            }
        }
        __builtin_amdgcn_s_setprio(0);

        // causal mask: kv_global > q_global <=> dkt*64 + kvl > qloc
        const int dkt = kt - 2*qt2;
        if (dkt >= 0) {
            const int qloc = wave*16 + cl;
            #pragma unroll
            for (int nf = 0; nf < 4; ++nf)
                #pragma unroll
                for (int r = 0; r < 4; ++r)
                    if (dkt*64 + nf*16 + g*4 + r > qloc) sac[nf][r] = -3.0e38f;
        }

        // row max of this tile (q = cl; reduce over g groups)
        float mx = -3.0e38f;
        #pragma unroll
        for (int nf = 0; nf < 4; ++nf)
            #pragma unroll
            for (int r = 0; r < 4; ++r) mx = fmaxf(mx, sac[nf][r]);
        mx = fmaxf(mx, __shfl_xor(mx, 16));
        mx = fmaxf(mx, __shfl_xor(mx, 32));

        // defer-max: only rescale when some row's max grew past m_i + 8
        if (!__all(mx - m_i <= 8.0f)) {
            const float mnew = fmaxf(m_i, mx);
            const float es = EXP2(m_i - mnew);
            l_i *= es;
            #pragma unroll
            for (int nf = 0; nf < 4; ++nf)
                #pragma unroll
                for (int r = 0; r < 4; ++r) oac[nf][r] *= es;
            m_i = mnew;
        }

        float ls = 0.f;
        #pragma unroll
        for (int nf = 0; nf < 4; ++nf) {
            float s0 = EXP2(sac[nf][0] - m_i);
            float s1 = EXP2(sac[nf][1] - m_i);
            float s2 = EXP2(sac[nf][2] - m_i);
            float s3 = EXP2(sac[nf][3] - m_i);
            sac[nf][0] = s0; sac[nf][1] = s1; sac[nf][2] = s2; sac[nf][3] = s3;
            ls += (s0 + s1) + (s2 + s3);
        }
        ls += __shfl_xor(ls, 16);
        ls += __shfl_xor(ls, 32);
        l_i += ls;

        int X[4], Y[4];
        #pragma unroll
        for (int nf = 0; nf < 4; ++nf) {
            X[nf] = cvt_pk_bf16(sac[nf][0], sac[nf][1]);
            Y[nf] = cvt_pk_bf16(sac[nf][2], sac[nf][3]);
        }

        const int sA = cl + ((g & 1) << 5);
        const bool hi = (g >> 1) != 0;
        __builtin_amdgcn_s_setprio(1);
        #pragma unroll
        for (int ks = 0; ks < 2; ++ks) {
            const int x0 = __shfl(X[2*ks],   sA);
            const int x1 = __shfl(X[2*ks+1], sA);
            const int y0 = __shfl(Y[2*ks],   sA);
            const int y1 = __shfl(Y[2*ks+1], sA);
            const int x2 = __shfl(X[2*ks],   sA + 16);
            const int x3 = __shfl(X[2*ks+1], sA + 16);
            const int y2 = __shfl(Y[2*ks],   sA + 16);
            const int y3 = __shfl(Y[2*ks+1], sA + 16);
            int4 w;
            w.x = hi ? x1 : x0;
            w.y = hi ? y1 : y0;
            w.z = hi ? x3 : x2;
            w.w = hi ? y3 : y2;
            const bf16x8 pb = __builtin_bit_cast(bf16x8, w);
            const int slot = ((ks*4 + g) ^ swz) * 8;
            #pragma unroll
            for (int nfd = 0; nfd < 4; ++nfd) {
                const bf16x8 vf =
                    *(const bf16x8*)&Vs[cur][(nfd*16 + cl)*64 + slot];
                oac[nfd] = __builtin_amdgcn_mfma_f32_16x16x32_bf16(
                    vf, pb, oac[nfd], 0, 0, 0);
            }
        }
        __builtin_amdgcn_s_setprio(0);
        cur ^= 1;
    }

    {
        const float inv = 1.f / l_i;
        const int srow = qt2*128 + wave*16 + cl;
        #pragma unroll
        for (int nf = 0; nf < 4; ++nf) {
            ush4 o4;
            #pragma unroll
            for (int r = 0; r < 4; ++r) o4[r] = f2b(oac[nf][r] * inv);
            *(ush4*)&out[(size_t)(b*S_ + srow)*D_ + h*HD_ + nf*16 + g*4] = o4;
        }
    }
}

// ---------------------------------------------------------------------------
extern "C" void kernel_launch(void* const* d_in, const int* in_sizes, int n_in,
                              void* d_out, int out_size, void* d_ws, size_t ws_size,
                              hipStream_t stream)
{
    const float* x    = (const float*)d_in[0];
    const float* Wq_w = (const float*)d_in[1];
    const float* Wq_b = (const float*)d_in[2];
    const float* Wk_w = (const float*)d_in[3];
    const float* Wk_b = (const float*)d_in[4];
    const float* Wv_w = (const float*)d_in[5];
    const float* Wv_b = (const float*)d_in[6];
    const float* Wo_w = (const float*)d_in[7];
    const float* Wo_b = (const float*)d_in[8];
    float* out = (float*)d_out;

    u16* xb    = (u16*)d_ws;                       // [M_][D_] bf16
    u16* wqt   = xb  + (size_t)M_*D_;              // [N][K] bf16
    u16* wkt   = wqt + (size_t)D_*D_;
    u16* wvt   = wkt + (size_t)D_*D_;
    u16* wot   = wvt + (size_t)D_*D_;
    u16* q     = wot + (size_t)D_*D_;              // [B,H,S,HD]
    u16* k     = q   + (size_t)M_*D_;              // [B,H,S,HD]
    u16* vt    = k   + (size_t)M_*D_;              // [B,H,HD,S]
    u16* attnb = vt  + (size_t)M_*D_;              // [M_][D_]

    cast_f32_bf16<<<2048, 256, 0, stream>>>(x, xb, M_*D_/8);
    transpose_cast4<<<dim3(16,16,4), 256, 0, stream>>>(
        Wq_w, Wk_w, Wv_w, Wo_w, wqt, wkt, wvt, wot);

    gemm_qkv128<<<dim3(M_/128, 24), 256, 0, stream>>>(
        xb, wqt, wkt, wvt, Wq_b, Wk_b, Wv_b, q, k, vt);

    attn_bf16<<<dim3(8, H_, B_), 512, 0, stream>>>(q, k, vt, attnb);

    gemm_oproj128<<<dim3(M_/128, D_/128), 256, 0, stream>>>(attnb, wot, Wo_b, out);
}